// Round 13
// baseline (2261.026 us; speedup 1.0000x reference)
//
#include <hip/hip_runtime.h>
#include <hip/hip_bf16.h>
#include <hip/hip_cooperative_groups.h>
#include <cstdint>
#include <cstddef>

namespace cg = cooperative_groups;

#define LN_EPS 1e-5f

typedef __attribute__((ext_vector_type(8))) short short8;
typedef __attribute__((ext_vector_type(4))) float f32x4;

__device__ __forceinline__ float gelu_exact(float x) {
  return 0.5f * x * (1.0f + erff(x * 0.70710678118654752440f));
}
__device__ __forceinline__ float bflo(unsigned int x) {
  union { unsigned int i; float f; } v; v.i = x << 16; return v.f;
}
__device__ __forceinline__ float bfhi(unsigned int x) {
  union { unsigned int i; float f; } v; v.i = x & 0xffff0000u; return v.f;
}
__device__ __forceinline__ float bf2f(short s) {
  union { unsigned int i; float f; } v; v.i = ((unsigned int)(unsigned short)s) << 16; return v.f;
}
__device__ __forceinline__ short bf16s(float f) {
  __hip_bfloat16 h = __float2bfloat16(f);
  return *reinterpret_cast<short*>(&h);
}

// ---- fused (y + a*k) -> LayerNorm(128) -> bf16 out  [proven; precompute lnsm] ----
__global__ __launch_bounds__(256) void ln_bf16_k(const float* __restrict__ X,
                                                 const float* __restrict__ KIN, float a,
                                                 const float* __restrict__ g,
                                                 const float* __restrict__ bb,
                                                 __hip_bfloat16* __restrict__ out, int rows) {
  int row = blockIdx.x * 4 + (threadIdx.x >> 6);
  if (row >= rows) return;
  int l = threadIdx.x & 63;
  size_t base = (size_t)row * 128;
  float x0 = X[base + l], x1 = X[base + l + 64];
  if (KIN) { x0 += a * KIN[base + l]; x1 += a * KIN[base + l + 64]; }
  float s = x0 + x1;
#pragma unroll
  for (int o = 32; o > 0; o >>= 1) s += __shfl_xor(s, o);
  float mu = s * (1.0f / 128.0f);
  float d0 = x0 - mu, d1 = x1 - mu;
  float v = d0 * d0 + d1 * d1;
#pragma unroll
  for (int o = 32; o > 0; o >>= 1) v += __shfl_xor(v, o);
  float rstd = rsqrtf(v * (1.0f / 128.0f) + LN_EPS);
  out[base + l] = __float2bfloat16(d0 * rstd * g[l] + bb[l]);
  out[base + l + 64] = __float2bfloat16(d1 * rstd * g[l + 64] + bb[l + 64]);
}

// ---- MFMA GEMM host kernel [proven; precompute folds only] ----
template <int ROWS, int BN, bool GELU_OUT, bool OUT_BF16>
__global__ __launch_bounds__(ROWS * 4) void gemm_mfma_k(
    const short* __restrict__ A, const short* __restrict__ WT,
    const float* __restrict__ bias, void* __restrict__ Cout,
    int K, int lda, int ldw, int ldc, float alpha,
    int hsA, int hsB, long hsC) {
  constexpr int T = ROWS * 4;
  constexpr int NFRAG = BN / 16;
  constexpr int NB = (BN * 8) / T;
  __shared__ __align__(16) short As[2][ROWS][72];
  __shared__ __align__(16) short Bs[2][BN][72];
  A += (size_t)blockIdx.z * hsA;
  WT += (size_t)blockIdx.z * hsB;
  const size_t cOff = (size_t)blockIdx.z * (size_t)hsC;
  const int tid = threadIdx.x;
  const int w = tid >> 6, l = tid & 63;
  const int row0 = blockIdx.y * ROWS, col0 = blockIdx.x * BN;
  f32x4 acc[NFRAG];
#pragma unroll
  for (int i = 0; i < NFRAG; ++i) acc[i] = (f32x4){0.f, 0.f, 0.f, 0.f};

  const int nt = K >> 6;
  short8 aR0, aR1;
  short8 bR[NB];
  auto loadA = [&](int t) {
    int k0 = t * 64;
    int c1 = tid + T;
    aR0 = *(const short8*)(A + (size_t)(row0 + (tid >> 3)) * lda + k0 + (tid & 7) * 8);
    aR1 = *(const short8*)(A + (size_t)(row0 + (c1 >> 3)) * lda + k0 + (c1 & 7) * 8);
  };
  auto loadB = [&](int t) {
    int k0 = t * 64;
#pragma unroll
    for (int i = 0; i < NB; ++i) {
      int c = tid + i * T;
      bR[i] = *(const short8*)(WT + (size_t)(col0 + (c >> 3)) * ldw + k0 + (c & 7) * 8);
    }
  };
  auto storeT = [&](int buf) {
    int c1 = tid + T;
    *(short8*)&As[buf][tid >> 3][(tid & 7) * 8] = aR0;
    *(short8*)&As[buf][c1 >> 3][(c1 & 7) * 8] = aR1;
#pragma unroll
    for (int i = 0; i < NB; ++i) {
      int c = tid + i * T;
      *(short8*)&Bs[buf][c >> 3][(c & 7) * 8] = bR[i];
    }
  };

  loadA(0);
  loadB(0);
  for (int t = 0; t < nt; ++t) {
    int buf = t & 1;
    storeT(buf);
    __syncthreads();
    if (t + 1 < nt) { loadA(t + 1); loadB(t + 1); }
    short8 af0 = *(const short8*)&As[buf][w * 16 + (l & 15)][(l >> 4) * 8];
    short8 af1 = *(const short8*)&As[buf][w * 16 + (l & 15)][(l >> 4) * 8 + 32];
#pragma unroll
    for (int nc = 0; nc < NFRAG; ++nc) {
      short8 bf0 = *(const short8*)&Bs[buf][nc * 16 + (l & 15)][(l >> 4) * 8];
      acc[nc] = __builtin_amdgcn_mfma_f32_16x16x32_bf16(af0, bf0, acc[nc], 0, 0, 0);
      short8 bf1 = *(const short8*)&Bs[buf][nc * 16 + (l & 15)][(l >> 4) * 8 + 32];
      acc[nc] = __builtin_amdgcn_mfma_f32_16x16x32_bf16(af1, bf1, acc[nc], 0, 0, 0);
    }
    __syncthreads();
  }
  const int cr = (l >> 4) * 4;
  const int cc = l & 15;
#pragma unroll
  for (int nc = 0; nc < NFRAG; ++nc) {
    int gc = col0 + nc * 16 + cc;
    float bv = bias ? bias[gc] : 0.0f;
#pragma unroll
    for (int r = 0; r < 4; ++r) {
      int gr = row0 + w * 16 + cr + r;
      float v = acc[nc][r] * alpha + bv;
      if (GELU_OUT) v = gelu_exact(v);
      if (OUT_BF16)
        ((__hip_bfloat16*)Cout)[cOff + (size_t)gr * ldc + gc] = __float2bfloat16(v);
      else
        ((float*)Cout)[cOff + (size_t)gr * ldc + gc] = v;
    }
  }
}

// ================= R13: cooperative solver megakernel =================
// Device GEMM: ROWS=64, 256 threads, double-buffered LDS — body verbatim from the
// proven gemm_mfma_k<64,BN> / gemm_heun_k. EPI 0: normal store; EPI 2: heun.
template <int BN, bool GELU_OUT, bool OUT_BF16, int EPI>
__device__ __forceinline__ void dev_gemm64(
    const short* __restrict__ A, const short* __restrict__ WT,
    const float* __restrict__ bias, void* __restrict__ Cout,
    int K, int lda, int ldw, int ldc, int tileX, int tileY, char* smem,
    const float* __restrict__ yin, const float* __restrict__ kaux, float c0) {
  constexpr int NFRAG = BN / 16;
  constexpr int NB = (BN * 8) / 256;
  short (*As)[64][72] = (short (*)[64][72])smem;
  short (*Bs)[BN][72] = (short (*)[BN][72])(smem + 18432);
  const int tid = threadIdx.x;
  const int w = tid >> 6, l = tid & 63;
  const int row0 = tileY * 64, col0 = tileX * BN;
  f32x4 acc[NFRAG];
#pragma unroll
  for (int i = 0; i < NFRAG; ++i) acc[i] = (f32x4){0.f, 0.f, 0.f, 0.f};
  const int nt = K >> 6;
  short8 aR0, aR1;
  short8 bR[NB];
  auto loadA = [&](int t) {
    int k0 = t * 64;
    int c1 = tid + 256;
    aR0 = *(const short8*)(A + (size_t)(row0 + (tid >> 3)) * lda + k0 + (tid & 7) * 8);
    aR1 = *(const short8*)(A + (size_t)(row0 + (c1 >> 3)) * lda + k0 + (c1 & 7) * 8);
  };
  auto loadB = [&](int t) {
    int k0 = t * 64;
#pragma unroll
    for (int i = 0; i < NB; ++i) {
      int c = tid + i * 256;
      bR[i] = *(const short8*)(WT + (size_t)(col0 + (c >> 3)) * ldw + k0 + (c & 7) * 8);
    }
  };
  auto storeT = [&](int buf) {
    int c1 = tid + 256;
    *(short8*)&As[buf][tid >> 3][(tid & 7) * 8] = aR0;
    *(short8*)&As[buf][c1 >> 3][(c1 & 7) * 8] = aR1;
#pragma unroll
    for (int i = 0; i < NB; ++i) {
      int c = tid + i * 256;
      *(short8*)&Bs[buf][c >> 3][(c & 7) * 8] = bR[i];
    }
  };
  loadA(0);
  loadB(0);
  for (int t = 0; t < nt; ++t) {
    int buf = t & 1;
    storeT(buf);
    __syncthreads();
    if (t + 1 < nt) { loadA(t + 1); loadB(t + 1); }
    short8 af0 = *(const short8*)&As[buf][w * 16 + (l & 15)][(l >> 4) * 8];
    short8 af1 = *(const short8*)&As[buf][w * 16 + (l & 15)][(l >> 4) * 8 + 32];
#pragma unroll
    for (int nc = 0; nc < NFRAG; ++nc) {
      short8 bf0 = *(const short8*)&Bs[buf][nc * 16 + (l & 15)][(l >> 4) * 8];
      acc[nc] = __builtin_amdgcn_mfma_f32_16x16x32_bf16(af0, bf0, acc[nc], 0, 0, 0);
      short8 bf1 = *(const short8*)&Bs[buf][nc * 16 + (l & 15)][(l >> 4) * 8 + 32];
      acc[nc] = __builtin_amdgcn_mfma_f32_16x16x32_bf16(af1, bf1, acc[nc], 0, 0, 0);
    }
    __syncthreads();
  }
  const int cr = (l >> 4) * 4, cc = l & 15;
#pragma unroll
  for (int nc = 0; nc < NFRAG; ++nc) {
    int gc = col0 + nc * 16 + cc;
    float bv = bias ? bias[gc] : 0.0f;
#pragma unroll
    for (int r = 0; r < 4; ++r) {
      int gr = row0 + w * 16 + cr + r;
      float v = acc[nc][r] + bv;
      if (GELU_OUT) v = gelu_exact(v);
      size_t idx = (size_t)gr * ldc + gc;
      if (EPI == 2) {
        ((float*)Cout)[idx] = yin[idx] + c0 * (kaux[idx] + v);
      } else if (OUT_BF16) {
        ((__hip_bfloat16*)Cout)[idx] = __float2bfloat16(v);
      } else {
        ((float*)Cout)[idx] = v;
      }
    }
  }
}

// Device zgemm: ROWS=64, K=1024, [h|mo]@Wg with LN fold epilogue [from proven R11].
__device__ __forceinline__ void dev_zgemm64(
    const short* __restrict__ hq, const short* __restrict__ mo,
    const float* __restrict__ ctxWg, const float* __restrict__ teWgRow,
    const float* __restrict__ u, const float* __restrict__ cbv,
    const float* __restrict__ murs, const short* __restrict__ WgT,
    short* __restrict__ outC, int tileX, int tileY, char* smem) {
  short (*As)[64][72] = (short (*)[64][72])smem;
  short (*Bs)[32][72] = (short (*)[32][72])(smem + 18432);
  const int tid = threadIdx.x;
  const int w = tid >> 6, l = tid & 63;
  const int row0 = tileY * 64, col0 = tileX * 32;
  const int rA0 = tid >> 3, rA1 = rA0 + 32, kc = (tid & 7) * 8;
  f32x4 acc[2];
  acc[0] = (f32x4){0.f, 0.f, 0.f, 0.f};
  acc[1] = (f32x4){0.f, 0.f, 0.f, 0.f};
  short8 aR0, aR1, bR;
  auto loadA = [&](int t) {
    const int k = t * 64 + kc;
    const short* src;
    int stride, koff;
    if (k < 512) { src = hq; stride = 1024; koff = k; }
    else         { src = mo; stride = 512;  koff = k - 512; }
    aR0 = *(const short8*)(src + (size_t)(row0 + rA0) * stride + koff);
    aR1 = *(const short8*)(src + (size_t)(row0 + rA1) * stride + koff);
  };
  auto loadB = [&](int t) {
    bR = *(const short8*)(WgT + (size_t)(col0 + (tid >> 3)) * 2048 + t * 64 + kc);
  };
  auto storeT = [&](int buf) {
    *(short8*)&As[buf][rA0][kc] = aR0;
    *(short8*)&As[buf][rA1][kc] = aR1;
    *(short8*)&Bs[buf][tid >> 3][kc] = bR;
  };
  loadA(0);
  loadB(0);
  for (int t = 0; t < 16; ++t) {
    int buf = t & 1;
    storeT(buf);
    __syncthreads();
    if (t + 1 < 16) { loadA(t + 1); loadB(t + 1); }
    short8 af0 = *(const short8*)&As[buf][w * 16 + (l & 15)][(l >> 4) * 8];
    short8 af1 = *(const short8*)&As[buf][w * 16 + (l & 15)][(l >> 4) * 8 + 32];
#pragma unroll
    for (int nc = 0; nc < 2; ++nc) {
      short8 bf0 = *(const short8*)&Bs[buf][nc * 16 + (l & 15)][(l >> 4) * 8];
      acc[nc] = __builtin_amdgcn_mfma_f32_16x16x32_bf16(af0, bf0, acc[nc], 0, 0, 0);
      short8 bf1 = *(const short8*)&Bs[buf][nc * 16 + (l & 15)][(l >> 4) * 8 + 32];
      acc[nc] = __builtin_amdgcn_mfma_f32_16x16x32_bf16(af1, bf1, acc[nc], 0, 0, 0);
    }
    __syncthreads();
  }
  const int cr = (l >> 4) * 4, cc = l & 15;
#pragma unroll
  for (int nc = 0; nc < 2; ++nc) {
    int gc = col0 + nc * 16 + cc;
    float uu = u[gc], cb = cbv[gc], tw = teWgRow[gc];
#pragma unroll
    for (int r = 0; r < 4; ++r) {
      int gr = row0 + w * 16 + cr + r;
      float mu = murs[2 * gr], rs = murs[2 * gr + 1];
      float v = rs * (acc[nc][r] + ctxWg[(size_t)gr * 512 + gc] + tw - mu * uu) + cb;
      outC[(size_t)gr * 512 + gc] = bf16s(gelu_exact(v));
    }
  }
}

// Device attention for one b [body verbatim from proven attn_k].
__device__ __forceinline__ void dev_attn(const __hip_bfloat16* __restrict__ hq,
                                         const short* __restrict__ lnsm,
                                         __hip_bfloat16* __restrict__ sctx,
                                         int b, char* smem) {
  short* smt = (short*)smem;                 // 16384 B
  float* qs = (float*)(smem + 16384);        // 2048 B
  float (*att)[64] = (float (*)[64])(smem + 18432);  // 1024 B
  const int tid = threadIdx.x;
  const int w = tid >> 6, l = tid & 63;
  {
    unsigned int u = ((const unsigned int*)(hq + (size_t)b * 1024 + 512))[tid];
    qs[2 * tid] = bflo(u);
    qs[2 * tid + 1] = bfhi(u);
  }
  {
    const int m = tid >> 2;
    const short* src = lnsm + ((size_t)b * 64 + m) * 128;
#pragma unroll
    for (int j = 0; j < 4; ++j) {
      int c = (tid & 3) + 4 * j;
      short8 v = *(const short8*)(src + c * 8);
      *(short8*)&smt[m * 128 + ((c ^ (m & 7)) * 8)] = v;
    }
  }
  __syncthreads();
  const float* qh = qs + w * 128;
  float acc = 0.f;
#pragma unroll
  for (int i = 0; i < 16; ++i) {
    uint4 u = *(const uint4*)&smt[l * 128 + ((i ^ (l & 7)) * 8)];
    const int d = i * 8;
    acc += bflo(u.x) * qh[d + 0] + bfhi(u.x) * qh[d + 1] +
           bflo(u.y) * qh[d + 2] + bfhi(u.y) * qh[d + 3] +
           bflo(u.z) * qh[d + 4] + bfhi(u.z) * qh[d + 5] +
           bflo(u.w) * qh[d + 6] + bfhi(u.w) * qh[d + 7];
  }
  float mx = acc;
#pragma unroll
  for (int o = 32; o > 0; o >>= 1) mx = fmaxf(mx, __shfl_xor(mx, o));
  float e = expf(acc - mx);
  float se = e;
#pragma unroll
  for (int o = 32; o > 0; o >>= 1) se += __shfl_xor(se, o);
  att[w][l] = e / se;
  const int cb = l >> 2, doff = 2 * (l & 3);
  float a0 = 0.f, a1 = 0.f;
#pragma unroll 8
  for (int m = 0; m < 64; ++m) {
    float am = att[w][m];
    unsigned int u = *(const unsigned int*)&smt[m * 128 + ((cb ^ (m & 7)) * 8) + doff];
    a0 += am * bflo(u);
    a1 += am * bfhi(u);
  }
  unsigned int pr = ((unsigned int)(unsigned short)bf16s(a1) << 16) |
                    (unsigned int)(unsigned short)bf16s(a0);
  ((unsigned int*)(sctx + (size_t)b * 512 + w * 128))[l] = pr;
}

struct SolverArgs {
  const float* ycur; const float* kin; float a;
  const float* ppg; const float* ppb; short* yln;
  const short* Wp1T; const float* bp1; short* hmid;
  const short* WhqT; const float* bhq; short* hqbuf;
  const short* lnsm; short* sctx;
  const short* WfoldT; const float* bofold; short* mobuf;
  const float* ctxsums; const float* teSums2; float* murs;
  const short* WgT; const float* ctxWg; const float* teWgRow;
  const float* uvec; const float* cbv; short* fmid;
  const short* Wf2T; const float* bf2;
  float* outY; const float* yin; const float* kaux; float c0;
};

// EPI 1: P8 writes v (k1, f32). EPI 2: P1 uses kin, P8 writes heun update.
template <int EPI>
__global__ __launch_bounds__(256) void solver_k(SolverArgs p) {
  __shared__ __align__(16) char smem[36864];
  cg::grid_group grid = cg::this_grid();
  const int blk = blockIdx.x;
  const int tid = threadIdx.x;

  // P1: yln = LN(y [+ a*kin]) bf16  [proven ln body]
  {
    int row = blk * 4 + (tid >> 6);
    int l = tid & 63;
    size_t base = (size_t)row * 128;
    float x0 = p.ycur[base + l], x1 = p.ycur[base + l + 64];
    if (EPI == 2) { x0 += p.a * p.kin[base + l]; x1 += p.a * p.kin[base + l + 64]; }
    float s = x0 + x1;
#pragma unroll
    for (int o = 32; o > 0; o >>= 1) s += __shfl_xor(s, o);
    float mu = s * (1.0f / 128.0f);
    float d0 = x0 - mu, d1 = x1 - mu;
    float v = d0 * d0 + d1 * d1;
#pragma unroll
    for (int o = 32; o > 0; o >>= 1) v += __shfl_xor(v, o);
    float rstd = rsqrtf(v * (1.0f / 128.0f) + LN_EPS);
    p.yln[base + l] = bf16s(d0 * rstd * p.ppg[l] + p.ppb[l]);
    p.yln[base + l + 64] = bf16s(d1 * rstd * p.ppg[l + 64] + p.ppb[l + 64]);
  }
  grid.sync();
  // P2: hmid = gelu(yln @ Wp1 + bp1)  (K=128)
  dev_gemm64<32, true, true, 0>(p.yln, p.Wp1T, p.bp1, p.hmid, 128, 128, 128, 512,
                                blk & 15, blk >> 4, smem, nullptr, nullptr, 0.f);
  grid.sync();
  // P3: [h|qp] = hmid @ WhqT + bhq  (K=512, N=1024)
  dev_gemm64<64, false, true, 0>(p.hmid, p.WhqT, p.bhq, p.hqbuf, 512, 512, 512, 1024,
                                 blk & 15, blk >> 4, smem, nullptr, nullptr, 0.f);
  grid.sync();
  // P4: attention (4 b per block)
  for (int i = 0; i < 4; ++i) {
    dev_attn((const __hip_bfloat16*)p.hqbuf, p.lnsm, (__hip_bfloat16*)p.sctx,
             blk * 4 + i, smem);
    __syncthreads();
  }
  grid.sync();
  // P5: mo = sctx @ Wfold + bofold  (K=512)
  dev_gemm64<32, false, true, 0>(p.sctx, p.WfoldT, p.bofold, p.mobuf, 512, 512, 512, 512,
                                 blk & 15, blk >> 4, smem, nullptr, nullptr, 0.f);
  grid.sync();
  // P6: zstats  [proven body]
  {
    int row = blk * 4 + (tid >> 6);
    int l = tid & 63;
    short8 hv = *(const short8*)(p.hqbuf + (size_t)row * 1024 + l * 8);
    short8 mv = *(const short8*)(p.mobuf + (size_t)row * 512 + l * 8);
    float s = 0.f, s2 = 0.f;
#pragma unroll
    for (int j = 0; j < 8; ++j) {
      float fa = bf2f(hv[j]), fb = bf2f(mv[j]);
      s += fa + fb;
      s2 += fa * fa + fb * fb;
    }
#pragma unroll
    for (int o = 32; o > 0; o >>= 1) { s += __shfl_xor(s, o); s2 += __shfl_xor(s2, o); }
    if (l == 0) {
      float S = s + p.ctxsums[2 * row] + p.teSums2[0];
      float S2 = s2 + p.ctxsums[2 * row + 1] + p.teSums2[1];
      float mu = S * (1.0f / 2048.0f);
      p.murs[2 * row] = mu;
      p.murs[2 * row + 1] = rsqrtf(S2 * (1.0f / 2048.0f) - mu * mu + LN_EPS);
    }
  }
  grid.sync();
  // P7: fmid = gelu(LN(z) @ Wf1 + bf1) via folded zgemm
  dev_zgemm64(p.hqbuf, p.mobuf, p.ctxWg, p.teWgRow, p.uvec, p.cbv, p.murs, p.WgT,
              p.fmid, blk & 15, blk >> 4, smem);
  grid.sync();
  // P8: out = fmid @ Wf2 + bf2 (EPI1: k1 f32; EPI2: heun)
  if (blk < 64) {
    if (EPI == 1) {
      dev_gemm64<32, false, false, 0>(p.fmid, p.Wf2T, p.bf2, p.outY, 512, 512, 512, 128,
                                      blk & 3, blk >> 2, smem, nullptr, nullptr, 0.f);
    } else {
      dev_gemm64<32, false, false, 2>(p.fmid, p.Wf2T, p.bf2, p.outY, 512, 512, 512, 128,
                                      blk & 3, blk >> 2, smem, p.yin, p.kaux, p.c0);
    }
  }
}

// ---- precompute helper kernels [all proven R12, verbatim] ----
struct TCBatch { const float* src[5]; short* dst[5]; };
__global__ __launch_bounds__(256) void transpose_cast_batch_k(TCBatch p) {
  const float* W = p.src[blockIdx.z];
  short* WT = p.dst[blockIdx.z];
  __shared__ float tile[64][65];
  int n0 = blockIdx.x * 64, k0 = blockIdx.y * 64;
#pragma unroll
  for (int i = 0; i < 16; ++i) {
    int e = threadIdx.x + i * 256;
    int r = e >> 6, c = e & 63;
    tile[r][c] = W[(size_t)(k0 + r) * 512 + n0 + c];
  }
  __syncthreads();
#pragma unroll
  for (int i = 0; i < 16; ++i) {
    int e = threadIdx.x + i * 256;
    int r = e >> 6, c = e & 63;
    WT[(size_t)(n0 + r) * 512 + k0 + c] = bf16s(tile[c][r]);
  }
}

__global__ __launch_bounds__(256) void transpose_cast_k(const float* __restrict__ W,
                                                        short* __restrict__ WT,
                                                        int K, int N) {
  __shared__ float tile[64][65];
  int n0 = blockIdx.x * 64, k0 = blockIdx.y * 64;
#pragma unroll
  for (int i = 0; i < 16; ++i) {
    int e = threadIdx.x + i * 256;
    int r = e >> 6, c = e & 63;
    tile[r][c] = W[(size_t)(k0 + r) * N + n0 + c];
  }
  __syncthreads();
#pragma unroll
  for (int i = 0; i < 16; ++i) {
    int e = threadIdx.x + i * 256;
    int r = e >> 6, c = e & 63;
    WT[(size_t)(n0 + r) * K + k0 + c] = bf16s(tile[c][r]);
  }
}

__global__ __launch_bounds__(256) void transpose_cast_scale_k(
    const float* __restrict__ W, const float* __restrict__ scale,
    short* __restrict__ WT, int K, int N) {
  __shared__ float tile[64][65];
  int n0 = blockIdx.x * 64, k0 = blockIdx.y * 64;
#pragma unroll
  for (int i = 0; i < 16; ++i) {
    int e = threadIdx.x + i * 256;
    int r = e >> 6, c = e & 63;
    tile[r][c] = W[(size_t)(k0 + r) * N + n0 + c] * scale[k0 + r];
  }
  __syncthreads();
#pragma unroll
  for (int i = 0; i < 16; ++i) {
    int e = threadIdx.x + i * 256;
    int r = e >> 6, c = e & 63;
    WT[(size_t)(n0 + r) * K + k0 + c] = bf16s(tile[c][r]);
  }
}

__global__ void cast_bf16_k(const float* __restrict__ src, short* __restrict__ dst, int n) {
  int i = blockIdx.x * blockDim.x + threadIdx.x;
  if (i < n) dst[i] = bf16s(src[i]);
}

__global__ __launch_bounds__(512) void vmp_k(const float* __restrict__ va,
                                             const float* __restrict__ vb,
                                             const float* __restrict__ W,
                                             int woff, int hsA,
                                             float* __restrict__ part) {
  const int j = threadIdx.x;
  const int b = blockIdx.x, z = blockIdx.z;
  const float* vaz = va + (size_t)z * hsA;
  float s = 0.f;
#pragma unroll 4
  for (int i = 0; i < 16; ++i) {
    int k = b * 16 + i;
    float c = vaz[k];
    if (vb) c *= vb[k];
    s += c * W[(size_t)(woff + k) * 512 + j];
  }
  part[((size_t)z * gridDim.x + b) * 512 + j] = s;
}

__global__ __launch_bounds__(512) void vmr_k(const float* __restrict__ part,
                                             const float* __restrict__ base, int KB,
                                             float* __restrict__ out, int hsOut) {
  const int j = threadIdx.x;
  const int z = blockIdx.z;
  float s = base ? base[j] : 0.f;
  for (int b = 0; b < KB; ++b) s += part[((size_t)z * KB + b) * 512 + j];
  out[(size_t)z * hsOut + j] = s;
}

__global__ __launch_bounds__(256) void bqp_k(const float* __restrict__ bhqq,
                                             const short* __restrict__ Wak_bf,
                                             float scale, float* __restrict__ bqp) {
  const int tid = threadIdx.x;
  const int j = blockIdx.x * 32 + (tid >> 3);
  const int h = j >> 7, e = j & 127;
  const int kl = tid & 7;
  float s = 0.f;
  for (int d = kl; d < 128; d += 8)
    s += bhqq[h * 128 + d] * bf2f(Wak_bf[(size_t)e * 512 + h * 128 + d]);
  s += __shfl_xor(s, 1);
  s += __shfl_xor(s, 2);
  s += __shfl_xor(s, 4);
  if (kl == 0) bqp[j] = s * scale;
}

__global__ __launch_bounds__(512) void te_k(const float* __restrict__ Wt,
                                            const float* __restrict__ bt,
                                            float* __restrict__ te,
                                            float* __restrict__ teSums) {
  __shared__ float emb[512];
  __shared__ float red[8];
  const int ci = blockIdx.x;
  const float t = 0.25f * (float)((ci >> 1) + (ci & 1));
  const int j = threadIdx.x;
  if (j < 256) {
    float fr = expf(-9.210340371976184f * (float)j * (1.0f / 255.0f));
    float ang = t * fr;
    emb[j] = sinf(ang);
    emb[j + 256] = cosf(ang);
  }
  __syncthreads();
  float s0 = 0.f, s1 = 0.f, s2 = 0.f, s3 = 0.f;
  for (int k = 0; k < 512; k += 4) {
    s0 += emb[k] * Wt[(size_t)k * 512 + j];
    s1 += emb[k + 1] * Wt[(size_t)(k + 1) * 512 + j];
    s2 += emb[k + 2] * Wt[(size_t)(k + 2) * 512 + j];
    s3 += emb[k + 3] * Wt[(size_t)(k + 3) * 512 + j];
  }
  float val = bt[j] + ((s0 + s1) + (s2 + s3));
  te[(size_t)ci * 512 + j] = val;
  float sv = val, sq = val * val;
#pragma unroll
  for (int o = 32; o > 0; o >>= 1) { sv += __shfl_xor(sv, o); sq += __shfl_xor(sq, o); }
  if ((j & 63) == 0) red[j >> 6] = sv;
  __syncthreads();
  if (j == 0) {
    float tot = 0.f;
    for (int i = 0; i < 8; ++i) tot += red[i];
    teSums[2 * ci] = tot;
  }
  __syncthreads();
  if ((j & 63) == 0) red[j >> 6] = sq;
  __syncthreads();
  if (j == 0) {
    float tot = 0.f;
    for (int i = 0; i < 8; ++i) tot += red[i];
    teSums[2 * ci + 1] = tot;
  }
}

__global__ __launch_bounds__(256) void rowsum_k(const short* __restrict__ X,
                                                float* __restrict__ sums, int rows) {
  int row = blockIdx.x * 4 + (threadIdx.x >> 6);
  if (row >= rows) return;
  int l = threadIdx.x & 63;
  short8 v = *(const short8*)(X + (size_t)row * 512 + l * 8);
  float s = 0.f, s2 = 0.f;
#pragma unroll
  for (int j = 0; j < 8; ++j) { float f = bf2f(v[j]); s += f; s2 += f * f; }
#pragma unroll
  for (int o = 32; o > 0; o >>= 1) { s += __shfl_xor(s, o); s2 += __shfl_xor(s2, o); }
  if (l == 0) { sums[2 * row] = s; sums[2 * row + 1] = s2; }
}

extern "C" void kernel_launch(void* const* d_in, const int* in_sizes, int n_in,
                              void* d_out, int out_size, void* d_ws, size_t ws_size,
                              hipStream_t stream) {
  (void)in_sizes; (void)n_in; (void)out_size; (void)ws_size;
  const int B = 1024, Mm = 64;
  const int BMrows = B * Mm;  // 65536
  const float ATTN_SCALE = 0.08838834764831845f;  // 1/sqrt(128)
  const size_t SL = (size_t)512 * 512;

  const float* noise = (const float*)d_in[0];
  const float* context = (const float*)d_in[1];
  const float* sm = (const float*)d_in[2];
  // d_in[3] = num_steps == 4 (fixed; dt = 0.25)
  const float* mem_ln_g = (const float*)d_in[4];
  const float* mem_ln_b = (const float*)d_in[5];
  const float* Wa = (const float*)d_in[6];
  const float* ba = (const float*)d_in[7];
  const float* Wq = (const float*)d_in[8];
  const float* bq = (const float*)d_in[9];
  const float* Wk = (const float*)d_in[10];
  const float* bk = (const float*)d_in[11];
  (void)bk;  // K bias constant over m -> softmax-invariant, dropped exactly
  const float* Wv = (const float*)d_in[12];
  const float* bv = (const float*)d_in[13];
  const float* Wo = (const float*)d_in[14];
  const float* bo = (const float*)d_in[15];
  const float* pp_ln_g = (const float*)d_in[16];
  const float* pp_ln_b = (const float*)d_in[17];
  const float* Wp1 = (const float*)d_in[18];
  const float* bp1 = (const float*)d_in[19];
  const float* Wp2 = (const float*)d_in[20];
  const float* bp2 = (const float*)d_in[21];
  const float* Wc = (const float*)d_in[22];
  const float* bc = (const float*)d_in[23];
  const float* Wt = (const float*)d_in[24];
  const float* bt = (const float*)d_in[25];
  const float* f_ln_g = (const float*)d_in[26];
  const float* f_ln_b = (const float*)d_in[27];
  const float* Wf1 = (const float*)d_in[28];
  const float* bf1 = (const float*)d_in[29];
  const float* Wf2 = (const float*)d_in[30];
  const float* bf2 = (const float*)d_in[31];
  float* out = (float*)d_out;

  char* wsb = (char*)d_ws;
  size_t off = 0;
  auto alloc = [&](size_t bytes) -> void* {
    off = (off + 255) & ~(size_t)255;
    void* p = wsb + off;
    off += bytes;
    return p;
  };
  short* lnsm = (short*)alloc((size_t)BMrows * 128 * 2);  // 16.8 MB
  short* T512 = (short*)alloc(4 * SL * 2);
  short* WkT = T512;
  short* WvT = T512 + SL;
  short* WqT = T512 + 2 * SL;
  short* WoT = T512 + 3 * SL;
  short* Wp1T = (short*)alloc((size_t)512 * 128 * 2);
  short* WhqT = (short*)alloc((size_t)1024 * 512 * 2);  // [Wp2T | WqpT]
  short* WfoldT = (short*)alloc(SL * 2);
  short* WcT = (short*)alloc((size_t)512 * 256 * 2);
  short* WgT = (short*)alloc((size_t)512 * 2048 * 2);  // (g ⊙ Wf1)^T
  short* Wf2T = (short*)alloc((size_t)128 * 512 * 2);
  short* WaB = (short*)alloc((size_t)128 * 512 * 2);
  short* Wp2B = (short*)alloc(SL * 2);
  short* WakavB = (short*)alloc(2 * (size_t)128 * 512 * 2);
  short* Wak_bf = WakavB;
  short* Wav_bf = WakavB + (size_t)128 * 512;
  short* Wp2q_bf = (short*)alloc(SL * 2);
  float* bhq = (float*)alloc(1024 * 4);
  float* bofold = (float*)alloc(512 * 4);
  float* bhqq = (float*)alloc(512 * 4);
  float* bav = (float*)alloc(512 * 4);
  float* te_table = (float*)alloc(8 * 512 * 4);
  float* teWg = (float*)alloc(8 * 512 * 4);
  float* teSums = (float*)alloc(16 * 4);
  float* uvec = (float*)alloc(512 * 4);
  float* cbv = (float*)alloc(512 * 4);
  float* vpart = (float*)alloc((size_t)8 * 128 * 512 * 4);
  float* ctxWg = (float*)alloc((size_t)B * 512 * 4);
  float* ctxsums = (float*)alloc((size_t)B * 2 * 4);
  float* murs = (float*)alloc((size_t)B * 2 * 4);
  short* ctxh = (short*)alloc((size_t)B * 512 * 2);
  float* k1 = (float*)alloc((size_t)B * 128 * 4);
  float* ybuf = (float*)alloc((size_t)B * 128 * 4);
  short* ctxb = (short*)alloc((size_t)B * 256 * 2);
  short* yln = (short*)alloc((size_t)B * 128 * 2);
  short* hmid = (short*)alloc((size_t)B * 512 * 2);
  short* hqbuf = (short*)alloc((size_t)B * 1024 * 2);
  short* sctx = (short*)alloc((size_t)B * 512 * 2);
  short* mobuf = (short*)alloc((size_t)B * 512 * 2);
  short* fmid = (short*)alloc((size_t)B * 512 * 2);

  // ================= precompute (solver-invariant) [identical to R12] ========
  ln_bf16_k<<<BMrows / 4, 256, 0, stream>>>(sm, nullptr, 0.f, mem_ln_g, mem_ln_b,
                                            (__hip_bfloat16*)lnsm, BMrows);
  cast_bf16_k<<<(128 * 512 + 255) / 256, 256, 0, stream>>>(Wa, WaB, 128 * 512);
  cast_bf16_k<<<(512 * 512 + 255) / 256, 256, 0, stream>>>(Wp2, Wp2B, 512 * 512);
  cast_bf16_k<<<(B * 256 + 255) / 256, 256, 0, stream>>>(context, ctxb, B * 256);
  {
    TCBatch p;
    p.src[0] = Wk; p.src[1] = Wv; p.src[2] = Wq; p.src[3] = Wo; p.src[4] = Wp2;
    p.dst[0] = WkT; p.dst[1] = WvT; p.dst[2] = WqT; p.dst[3] = WoT; p.dst[4] = WhqT;
    transpose_cast_batch_k<<<dim3(8, 8, 5), 256, 0, stream>>>(p);
  }
  transpose_cast_k<<<dim3(8, 2), 256, 0, stream>>>(Wp1, Wp1T, 128, 512);
  transpose_cast_k<<<dim3(8, 4), 256, 0, stream>>>(Wc, WcT, 256, 512);
  transpose_cast_scale_k<<<dim3(8, 32), 256, 0, stream>>>(Wf1, f_ln_g, WgT, 2048, 512);
  transpose_cast_k<<<dim3(2, 8), 256, 0, stream>>>(Wf2, Wf2T, 512, 128);
  gemm_mfma_k<64, 64, false, true><<<dim3(8, 2, 2), 256, 0, stream>>>(
      WaB, WkT, nullptr, WakavB, 512, 512, 512, 512, 1.f, 0, (int)SL, 128 * 512);
  gemm_mfma_k<64, 64, false, true><<<dim3(8, 8), 256, 0, stream>>>(
      Wp2B, WqT, nullptr, Wp2q_bf, 512, 512, 512, 512, 1.f, 0, 0, 0);
  gemm_mfma_k<64, 64, false, true><<<dim3(8, 2, 4), 256, 0, stream>>>(
      Wak_bf, Wp2q_bf, nullptr, WhqT + SL, 128, 512, 512, 512, ATTN_SCALE,
      128, 128, 128 * 512);
  gemm_mfma_k<64, 64, false, true><<<dim3(2, 8, 4), 256, 0, stream>>>(
      WoT, Wav_bf, nullptr, WfoldT, 128, 512, 512, 512, 1.f, 128, 128, 128);
  vmp_k<<<dim3(32, 1, 1), 512, 0, stream>>>(bp2, nullptr, Wq, 0, 0, vpart);
  vmr_k<<<dim3(1, 1, 1), 512, 0, stream>>>(vpart, bq, 32, bhqq, 512);
  bqp_k<<<16, 256, 0, stream>>>(bhqq, Wak_bf, ATTN_SCALE, bhq + 512);
  hipMemcpyAsync(bhq, bp2, 512 * 4, hipMemcpyDeviceToDevice, stream);
  vmp_k<<<dim3(32, 1, 1), 512, 0, stream>>>(ba, nullptr, Wv, 0, 0, vpart);
  vmr_k<<<dim3(1, 1, 1), 512, 0, stream>>>(vpart, bv, 32, bav, 512);
  vmp_k<<<dim3(32, 1, 1), 512, 0, stream>>>(bav, nullptr, Wo, 0, 0, vpart);
  vmr_k<<<dim3(1, 1, 1), 512, 0, stream>>>(vpart, bo, 32, bofold, 512);
  gemm_mfma_k<64, 64, false, true><<<dim3(8, 16), 256, 0, stream>>>(
      ctxb, WcT, bc, ctxh, 256, 256, 256, 512, 1.f, 0, 0, 0);
  te_k<<<8, 512, 0, stream>>>(Wt, bt, te_table, teSums);
  vmp_k<<<dim3(128, 1, 1), 512, 0, stream>>>(f_ln_g, nullptr, Wf1, 0, 0, vpart);
  vmr_k<<<dim3(1, 1, 1), 512, 0, stream>>>(vpart, nullptr, 128, uvec, 512);
  vmp_k<<<dim3(128, 1, 1), 512, 0, stream>>>(f_ln_b, nullptr, Wf1, 0, 0, vpart);
  vmr_k<<<dim3(1, 1, 1), 512, 0, stream>>>(vpart, bf1, 128, cbv, 512);
  vmp_k<<<dim3(32, 1, 8), 512, 0, stream>>>(te_table, f_ln_g + 1536, Wf1, 1536, 512, vpart);
  vmr_k<<<dim3(1, 1, 8), 512, 0, stream>>>(vpart, nullptr, 32, teWg, 512);
  gemm_mfma_k<64, 64, false, false><<<dim3(8, 16), 256, 0, stream>>>(
      ctxh, WgT + 1024, nullptr, ctxWg, 512, 512, 2048, 512, 1.f, 0, 0, 0);
  rowsum_k<<<B / 4, 256, 0, stream>>>(ctxh, ctxsums, B);

  // ================= solver: 8 cooperative megakernel launches ===============
  const float dt = 0.25f;
  const float* ycur = noise;
  for (int s = 0; s < 4; ++s) {
    // eval 1: k1 = v(y, t0)
    {
      SolverArgs a;
      a.ycur = ycur; a.kin = nullptr; a.a = 0.f;
      a.ppg = pp_ln_g; a.ppb = pp_ln_b; a.yln = yln;
      a.Wp1T = Wp1T; a.bp1 = bp1; a.hmid = hmid;
      a.WhqT = WhqT; a.bhq = bhq; a.hqbuf = hqbuf;
      a.lnsm = lnsm; a.sctx = sctx;
      a.WfoldT = WfoldT; a.bofold = bofold; a.mobuf = mobuf;
      a.ctxsums = ctxsums; a.teSums2 = teSums + 2 * (2 * s); a.murs = murs;
      a.WgT = WgT; a.ctxWg = ctxWg; a.teWgRow = teWg + (size_t)(2 * s) * 512;
      a.uvec = uvec; a.cbv = cbv; a.fmid = fmid;
      a.Wf2T = Wf2T; a.bf2 = bf2;
      a.outY = k1; a.yin = nullptr; a.kaux = nullptr; a.c0 = 0.f;
      void* params[] = {&a};
      hipLaunchCooperativeKernel((void*)solver_k<1>, dim3(256), dim3(256),
                                 params, 0, stream);
    }
    // eval 2: LN(y + dt*k1); ynext = y + dt/2*(k1 + v2)
    {
      float* ynext = (s == 3) ? out : ybuf;
      SolverArgs a;
      a.ycur = ycur; a.kin = k1; a.a = dt;
      a.ppg = pp_ln_g; a.ppb = pp_ln_b; a.yln = yln;
      a.Wp1T = Wp1T; a.bp1 = bp1; a.hmid = hmid;
      a.WhqT = WhqT; a.bhq = bhq; a.hqbuf = hqbuf;
      a.lnsm = lnsm; a.sctx = sctx;
      a.WfoldT = WfoldT; a.bofold = bofold; a.mobuf = mobuf;
      a.ctxsums = ctxsums; a.teSums2 = teSums + 2 * (2 * s + 1); a.murs = murs;
      a.WgT = WgT; a.ctxWg = ctxWg; a.teWgRow = teWg + (size_t)(2 * s + 1) * 512;
      a.uvec = uvec; a.cbv = cbv; a.fmid = fmid;
      a.Wf2T = Wf2T; a.bf2 = bf2;
      a.outY = ynext; a.yin = ycur; a.kaux = k1; a.c0 = 0.5f * dt;
      void* params[] = {&a};
      hipLaunchCooperativeKernel((void*)solver_k<2>, dim3(256), dim3(256),
                                 params, 0, stream);
    }
    ycur = ybuf;
  }
}

// Round 14
// 620.733 us; speedup vs baseline: 3.6425x; 3.6425x over previous
//
#include <hip/hip_runtime.h>
#include <hip/hip_bf16.h>
#include <cstdint>
#include <cstddef>

#define LN_EPS 1e-5f

typedef __attribute__((ext_vector_type(8))) short short8;
typedef __attribute__((ext_vector_type(4))) float f32x4;

__device__ __forceinline__ float gelu_exact(float x) {
  return 0.5f * x * (1.0f + erff(x * 0.70710678118654752440f));
}
__device__ __forceinline__ float bflo(unsigned int x) {
  union { unsigned int i; float f; } v; v.i = x << 16; return v.f;
}
__device__ __forceinline__ float bfhi(unsigned int x) {
  union { unsigned int i; float f; } v; v.i = x & 0xffff0000u; return v.f;
}
__device__ __forceinline__ float bf2f(short s) {
  union { unsigned int i; float f; } v; v.i = ((unsigned int)(unsigned short)s) << 16; return v.f;
}
__device__ __forceinline__ short bf16s(float f) {
  __hip_bfloat16 h = __float2bfloat16(f);
  return *reinterpret_cast<short*>(&h);
}

// ---- fused (y + a*k) -> LayerNorm(128) -> bf16 out  [proven] ----
__global__ __launch_bounds__(256) void ln_bf16_k(const float* __restrict__ X,
                                                 const float* __restrict__ KIN, float a,
                                                 const float* __restrict__ g,
                                                 const float* __restrict__ bb,
                                                 __hip_bfloat16* __restrict__ out, int rows) {
  int row = blockIdx.x * 4 + (threadIdx.x >> 6);
  if (row >= rows) return;
  int l = threadIdx.x & 63;
  size_t base = (size_t)row * 128;
  float x0 = X[base + l], x1 = X[base + l + 64];
  if (KIN) { x0 += a * KIN[base + l]; x1 += a * KIN[base + l + 64]; }
  float s = x0 + x1;
#pragma unroll
  for (int o = 32; o > 0; o >>= 1) s += __shfl_xor(s, o);
  float mu = s * (1.0f / 128.0f);
  float d0 = x0 - mu, d1 = x1 - mu;
  float v = d0 * d0 + d1 * d1;
#pragma unroll
  for (int o = 32; o > 0; o >>= 1) v += __shfl_xor(v, o);
  float rstd = rsqrtf(v * (1.0f / 128.0f) + LN_EPS);
  out[base + l] = __float2bfloat16(d0 * rstd * g[l] + bb[l]);
  out[base + l + 64] = __float2bfloat16(d1 * rstd * g[l + 64] + bb[l + 64]);
}

// ---- MFMA GEMM, BK=64, double-buffered LDS [proven] ----
template <int ROWS, int BN, bool GELU_OUT, bool OUT_BF16>
__global__ __launch_bounds__(ROWS * 4) void gemm_mfma_k(
    const short* __restrict__ A, const short* __restrict__ WT,
    const float* __restrict__ bias, void* __restrict__ Cout,
    int K, int lda, int ldw, int ldc, float alpha,
    int hsA, int hsB, long hsC) {
  constexpr int T = ROWS * 4;
  constexpr int NFRAG = BN / 16;
  constexpr int NB = (BN * 8) / T;
  __shared__ __align__(16) short As[2][ROWS][72];
  __shared__ __align__(16) short Bs[2][BN][72];
  A += (size_t)blockIdx.z * hsA;
  WT += (size_t)blockIdx.z * hsB;
  const size_t cOff = (size_t)blockIdx.z * (size_t)hsC;
  const int tid = threadIdx.x;
  const int w = tid >> 6, l = tid & 63;
  const int row0 = blockIdx.y * ROWS, col0 = blockIdx.x * BN;
  f32x4 acc[NFRAG];
#pragma unroll
  for (int i = 0; i < NFRAG; ++i) acc[i] = (f32x4){0.f, 0.f, 0.f, 0.f};

  const int nt = K >> 6;
  short8 aR0, aR1;
  short8 bR[NB];
  auto loadA = [&](int t) {
    int k0 = t * 64;
    int c1 = tid + T;
    aR0 = *(const short8*)(A + (size_t)(row0 + (tid >> 3)) * lda + k0 + (tid & 7) * 8);
    aR1 = *(const short8*)(A + (size_t)(row0 + (c1 >> 3)) * lda + k0 + (c1 & 7) * 8);
  };
  auto loadB = [&](int t) {
    int k0 = t * 64;
#pragma unroll
    for (int i = 0; i < NB; ++i) {
      int c = tid + i * T;
      bR[i] = *(const short8*)(WT + (size_t)(col0 + (c >> 3)) * ldw + k0 + (c & 7) * 8);
    }
  };
  auto storeT = [&](int buf) {
    int c1 = tid + T;
    *(short8*)&As[buf][tid >> 3][(tid & 7) * 8] = aR0;
    *(short8*)&As[buf][c1 >> 3][(c1 & 7) * 8] = aR1;
#pragma unroll
    for (int i = 0; i < NB; ++i) {
      int c = tid + i * T;
      *(short8*)&Bs[buf][c >> 3][(c & 7) * 8] = bR[i];
    }
  };

  loadA(0);
  loadB(0);
  for (int t = 0; t < nt; ++t) {
    int buf = t & 1;
    storeT(buf);
    __syncthreads();
    if (t + 1 < nt) { loadA(t + 1); loadB(t + 1); }
    short8 af0 = *(const short8*)&As[buf][w * 16 + (l & 15)][(l >> 4) * 8];
    short8 af1 = *(const short8*)&As[buf][w * 16 + (l & 15)][(l >> 4) * 8 + 32];
#pragma unroll
    for (int nc = 0; nc < NFRAG; ++nc) {
      short8 bf0 = *(const short8*)&Bs[buf][nc * 16 + (l & 15)][(l >> 4) * 8];
      acc[nc] = __builtin_amdgcn_mfma_f32_16x16x32_bf16(af0, bf0, acc[nc], 0, 0, 0);
      short8 bf1 = *(const short8*)&Bs[buf][nc * 16 + (l & 15)][(l >> 4) * 8 + 32];
      acc[nc] = __builtin_amdgcn_mfma_f32_16x16x32_bf16(af1, bf1, acc[nc], 0, 0, 0);
    }
    __syncthreads();
  }
  const int cr = (l >> 4) * 4;
  const int cc = l & 15;
#pragma unroll
  for (int nc = 0; nc < NFRAG; ++nc) {
    int gc = col0 + nc * 16 + cc;
    float bv = bias ? bias[gc] : 0.0f;
#pragma unroll
    for (int r = 0; r < 4; ++r) {
      int gr = row0 + w * 16 + cr + r;
      float v = acc[nc][r] * alpha + bv;
      if (GELU_OUT) v = gelu_exact(v);
      if (OUT_BF16)
        ((__hip_bfloat16*)Cout)[cOff + (size_t)gr * ldc + gc] = __float2bfloat16(v);
      else
        ((float*)Cout)[cOff + (size_t)gr * ldc + gc] = v;
    }
  }
}

// ---- R14: [h|mo] @ Wg_hm with LN folded epilogue AND in-kernel stats pass-1.
// Pass-1 = proven zstats_k math per-block (R10-proven in-kernel pattern);
// main loop + epilogue = proven R11/R12 zgemm2 with mu/rs from LDS.
__global__ __launch_bounds__(128) void zgemm2_k(
    const short* __restrict__ hq, const short* __restrict__ mo,
    const float* __restrict__ ctxWg, const float* __restrict__ teWgRow,
    const float* __restrict__ u, const float* __restrict__ cbv,
    const float* __restrict__ ctxsums, const float* __restrict__ teSums2,
    const short* __restrict__ WgT, short* __restrict__ outC) {
  __shared__ __align__(16) short As[2][32][72];
  __shared__ __align__(16) short Bs[2][32][72];
  __shared__ float muS[32], rsS[32];
  const int tid = threadIdx.x;
  const int w = tid >> 6, l = tid & 63;
  const int row0 = blockIdx.y * 32, col0 = blockIdx.x * 32;
  // ---- pass 1: LN(2048) stats for this block's 32 rows (4 thr/row) ----
  {
    const int r = tid >> 2, q = tid & 3;
    const short* ph = hq + (size_t)(row0 + r) * 1024 + q * 256;
    const short* pm = mo + (size_t)(row0 + r) * 512 + q * 128;
    float s = 0.f, s2 = 0.f;
#pragma unroll 4
    for (int i = 0; i < 32; ++i) {
      short8 a = *(const short8*)(ph + i * 8);
#pragma unroll
      for (int j = 0; j < 8; ++j) { float f = bf2f(a[j]); s += f; s2 += f * f; }
    }
#pragma unroll 4
    for (int i = 0; i < 16; ++i) {
      short8 b = *(const short8*)(pm + i * 8);
#pragma unroll
      for (int j = 0; j < 8; ++j) { float f = bf2f(b[j]); s += f; s2 += f * f; }
    }
    s += __shfl_xor(s, 1); s += __shfl_xor(s, 2);
    s2 += __shfl_xor(s2, 1); s2 += __shfl_xor(s2, 2);
    if (q == 0) {
      float S = s + ctxsums[2 * (row0 + r)] + teSums2[0];
      float S2 = s2 + ctxsums[2 * (row0 + r) + 1] + teSums2[1];
      float mu = S * (1.0f / 2048.0f);
      muS[r] = mu;
      rsS[r] = rsqrtf(S2 * (1.0f / 2048.0f) - mu * mu + LN_EPS);
    }
  }
  __syncthreads();

  const int rA0 = tid >> 3, rA1 = rA0 + 16, kc = (tid & 7) * 8;
  f32x4 acc[2];
  acc[0] = (f32x4){0.f, 0.f, 0.f, 0.f};
  acc[1] = (f32x4){0.f, 0.f, 0.f, 0.f};
  short8 aR0, aR1;
  short8 bR[2];
  auto loadA = [&](int t) {
    const int k = t * 64 + kc;
    const short* src;
    int stride, koff;
    if (k < 512) { src = hq; stride = 1024; koff = k; }
    else         { src = mo; stride = 512;  koff = k - 512; }
    aR0 = *(const short8*)(src + (size_t)(row0 + rA0) * stride + koff);
    aR1 = *(const short8*)(src + (size_t)(row0 + rA1) * stride + koff);
  };
  auto loadB = [&](int t) {
    int k0 = t * 64;
#pragma unroll
    for (int i = 0; i < 2; ++i) {
      int c = tid + i * 128;
      bR[i] = *(const short8*)(WgT + (size_t)(col0 + (c >> 3)) * 2048 + k0 + (c & 7) * 8);
    }
  };
  auto storeT = [&](int buf) {
    *(short8*)&As[buf][rA0][kc] = aR0;
    *(short8*)&As[buf][rA1][kc] = aR1;
#pragma unroll
    for (int i = 0; i < 2; ++i) {
      int c = tid + i * 128;
      *(short8*)&Bs[buf][c >> 3][(c & 7) * 8] = bR[i];
    }
  };

  loadA(0);
  loadB(0);
  for (int t = 0; t < 16; ++t) {
    int buf = t & 1;
    storeT(buf);
    __syncthreads();
    if (t + 1 < 16) { loadA(t + 1); loadB(t + 1); }
    short8 af0 = *(const short8*)&As[buf][w * 16 + (l & 15)][(l >> 4) * 8];
    short8 af1 = *(const short8*)&As[buf][w * 16 + (l & 15)][(l >> 4) * 8 + 32];
#pragma unroll
    for (int nc = 0; nc < 2; ++nc) {
      short8 bf0 = *(const short8*)&Bs[buf][nc * 16 + (l & 15)][(l >> 4) * 8];
      acc[nc] = __builtin_amdgcn_mfma_f32_16x16x32_bf16(af0, bf0, acc[nc], 0, 0, 0);
      short8 bf1 = *(const short8*)&Bs[buf][nc * 16 + (l & 15)][(l >> 4) * 8 + 32];
      acc[nc] = __builtin_amdgcn_mfma_f32_16x16x32_bf16(af1, bf1, acc[nc], 0, 0, 0);
    }
    __syncthreads();
  }
  const int cr = (l >> 4) * 4, cc = l & 15;
#pragma unroll
  for (int nc = 0; nc < 2; ++nc) {
    int gc = col0 + nc * 16 + cc;
    float uu = u[gc], cb = cbv[gc], tw = teWgRow[gc];
#pragma unroll
    for (int r = 0; r < 4; ++r) {
      int lr = w * 16 + cr + r;
      int gr = row0 + lr;
      float mu = muS[lr], rs = rsS[lr];
      float v = rs * (acc[nc][r] + ctxWg[(size_t)gr * 512 + gc] + tw - mu * uu) + cb;
      outC[(size_t)gr * 512 + gc] = bf16s(gelu_exact(v));
    }
  }
}

// ---- per-row sum/sumsq of (rows x 512) bf16 [proven] ----
__global__ __launch_bounds__(256) void rowsum_k(const short* __restrict__ X,
                                                float* __restrict__ sums, int rows) {
  int row = blockIdx.x * 4 + (threadIdx.x >> 6);
  if (row >= rows) return;
  int l = threadIdx.x & 63;
  short8 v = *(const short8*)(X + (size_t)row * 512 + l * 8);
  float s = 0.f, s2 = 0.f;
#pragma unroll
  for (int j = 0; j < 8; ++j) { float f = bf2f(v[j]); s += f; s2 += f * f; }
#pragma unroll
  for (int o = 32; o > 0; o >>= 1) { s += __shfl_xor(s, o); s2 += __shfl_xor(s2, o); }
  if (l == 0) { sums[2 * row] = s; sums[2 * row + 1] = s2; }
}

// ---- coalesced vec@mat stage 1 [proven R12] ----
__global__ __launch_bounds__(512) void vmp_k(const float* __restrict__ va,
                                             const float* __restrict__ vb,
                                             const float* __restrict__ W,
                                             int woff, int hsA,
                                             float* __restrict__ part) {
  const int j = threadIdx.x;
  const int b = blockIdx.x, z = blockIdx.z;
  const float* vaz = va + (size_t)z * hsA;
  float s = 0.f;
#pragma unroll 4
  for (int i = 0; i < 16; ++i) {
    int k = b * 16 + i;
    float c = vaz[k];
    if (vb) c *= vb[k];
    s += c * W[(size_t)(woff + k) * 512 + j];
  }
  part[((size_t)z * gridDim.x + b) * 512 + j] = s;
}

// ---- vec@mat stage 2 [proven R12] ----
__global__ __launch_bounds__(512) void vmr_k(const float* __restrict__ part,
                                             const float* __restrict__ base, int KB,
                                             float* __restrict__ out, int hsOut) {
  const int j = threadIdx.x;
  const int z = blockIdx.z;
  float s = base ? base[j] : 0.f;
  for (int b = 0; b < KB; ++b) s += part[((size_t)z * KB + b) * 512 + j];
  out[(size_t)z * hsOut + j] = s;
}

// ---- transpose + cast with row scale [proven] ----
__global__ __launch_bounds__(256) void transpose_cast_scale_k(
    const float* __restrict__ W, const float* __restrict__ scale,
    short* __restrict__ WT, int K, int N) {
  __shared__ float tile[64][65];
  int n0 = blockIdx.x * 64, k0 = blockIdx.y * 64;
#pragma unroll
  for (int i = 0; i < 16; ++i) {
    int e = threadIdx.x + i * 256;
    int r = e >> 6, c = e & 63;
    tile[r][c] = W[(size_t)(k0 + r) * N + n0 + c] * scale[k0 + r];
  }
  __syncthreads();
#pragma unroll
  for (int i = 0; i < 16; ++i) {
    int e = threadIdx.x + i * 256;
    int r = e >> 6, c = e & 63;
    WT[(size_t)(n0 + r) * K + k0 + c] = bf16s(tile[c][r]);
  }
}

// ---- GEMM (Wf2) + Heun epilogue [proven] ----
__global__ __launch_bounds__(256) void gemm_heun_k(
    const short* __restrict__ A, const short* __restrict__ WT,
    const float* __restrict__ bias, const float* __restrict__ yin,
    const float* __restrict__ kaux, float c0, float* __restrict__ outY) {
  __shared__ __align__(16) short As[2][64][72];
  __shared__ __align__(16) short Bs[2][32][72];
  const int tid = threadIdx.x;
  const int w = tid >> 6, l = tid & 63;
  const int row0 = blockIdx.y * 64, col0 = blockIdx.x * 32;
  f32x4 acc[2];
  acc[0] = (f32x4){0.f, 0.f, 0.f, 0.f};
  acc[1] = (f32x4){0.f, 0.f, 0.f, 0.f};
  short8 aR0, aR1, bR;
  auto loadA = [&](int t) {
    int k0 = t * 64;
    int c1 = tid + 256;
    aR0 = *(const short8*)(A + (size_t)(row0 + (tid >> 3)) * 512 + k0 + (tid & 7) * 8);
    aR1 = *(const short8*)(A + (size_t)(row0 + (c1 >> 3)) * 512 + k0 + (c1 & 7) * 8);
  };
  auto loadB = [&](int t) {
    int k0 = t * 64;
    bR = *(const short8*)(WT + (size_t)(col0 + (tid >> 3)) * 512 + k0 + (tid & 7) * 8);
  };
  auto storeT = [&](int buf) {
    int c1 = tid + 256;
    *(short8*)&As[buf][tid >> 3][(tid & 7) * 8] = aR0;
    *(short8*)&As[buf][c1 >> 3][(c1 & 7) * 8] = aR1;
    *(short8*)&Bs[buf][tid >> 3][(tid & 7) * 8] = bR;
  };
  loadA(0);
  loadB(0);
  for (int t = 0; t < 8; ++t) {
    int buf = t & 1;
    storeT(buf);
    __syncthreads();
    if (t + 1 < 8) { loadA(t + 1); loadB(t + 1); }
    short8 af0 = *(const short8*)&As[buf][w * 16 + (l & 15)][(l >> 4) * 8];
    short8 af1 = *(const short8*)&As[buf][w * 16 + (l & 15)][(l >> 4) * 8 + 32];
#pragma unroll
    for (int nc = 0; nc < 2; ++nc) {
      short8 bf0 = *(const short8*)&Bs[buf][nc * 16 + (l & 15)][(l >> 4) * 8];
      acc[nc] = __builtin_amdgcn_mfma_f32_16x16x32_bf16(af0, bf0, acc[nc], 0, 0, 0);
      short8 bf1 = *(const short8*)&Bs[buf][nc * 16 + (l & 15)][(l >> 4) * 8 + 32];
      acc[nc] = __builtin_amdgcn_mfma_f32_16x16x32_bf16(af1, bf1, acc[nc], 0, 0, 0);
    }
    __syncthreads();
  }
  const int cr = (l >> 4) * 4, cc = l & 15;
#pragma unroll
  for (int nc = 0; nc < 2; ++nc) {
    int gc = col0 + nc * 16 + cc;
    float bv = bias[gc];
#pragma unroll
    for (int r = 0; r < 4; ++r) {
      int gr = row0 + w * 16 + cr + r;
      float v = acc[nc][r] + bv;
      size_t idx = (size_t)gr * 128 + gc;
      outY[idx] = yin[idx] + c0 * (kaux[idx] + v);
    }
  }
}

// ---- batched transpose+cast [proven] ----
struct TCBatch { const float* src[5]; short* dst[5]; };
__global__ __launch_bounds__(256) void transpose_cast_batch_k(TCBatch p) {
  const float* W = p.src[blockIdx.z];
  short* WT = p.dst[blockIdx.z];
  __shared__ float tile[64][65];
  int n0 = blockIdx.x * 64, k0 = blockIdx.y * 64;
#pragma unroll
  for (int i = 0; i < 16; ++i) {
    int e = threadIdx.x + i * 256;
    int r = e >> 6, c = e & 63;
    tile[r][c] = W[(size_t)(k0 + r) * 512 + n0 + c];
  }
  __syncthreads();
#pragma unroll
  for (int i = 0; i < 16; ++i) {
    int e = threadIdx.x + i * 256;
    int r = e >> 6, c = e & 63;
    WT[(size_t)(n0 + r) * 512 + k0 + c] = bf16s(tile[c][r]);
  }
}

// ---- generic transpose + cast [proven] ----
__global__ __launch_bounds__(256) void transpose_cast_k(const float* __restrict__ W,
                                                        short* __restrict__ WT,
                                                        int K, int N) {
  __shared__ float tile[64][65];
  int n0 = blockIdx.x * 64, k0 = blockIdx.y * 64;
#pragma unroll
  for (int i = 0; i < 16; ++i) {
    int e = threadIdx.x + i * 256;
    int r = e >> 6, c = e & 63;
    tile[r][c] = W[(size_t)(k0 + r) * N + n0 + c];
  }
  __syncthreads();
#pragma unroll
  for (int i = 0; i < 16; ++i) {
    int e = threadIdx.x + i * 256;
    int r = e >> 6, c = e & 63;
    WT[(size_t)(n0 + r) * K + k0 + c] = bf16s(tile[c][r]);
  }
}

__global__ void cast_bf16_k(const float* __restrict__ src, short* __restrict__ dst, int n) {
  int i = blockIdx.x * blockDim.x + threadIdx.x;
  if (i < n) dst[i] = bf16s(src[i]);
}

// ---- bqp [proven; small K=128] ----
__global__ __launch_bounds__(256) void bqp_k(const float* __restrict__ bhqq,
                                             const short* __restrict__ Wak_bf,
                                             float scale, float* __restrict__ bqp) {
  const int tid = threadIdx.x;
  const int j = blockIdx.x * 32 + (tid >> 3);
  const int h = j >> 7, e = j & 127;
  const int kl = tid & 7;
  float s = 0.f;
  for (int d = kl; d < 128; d += 8)
    s += bhqq[h * 128 + d] * bf2f(Wak_bf[(size_t)e * 512 + h * 128 + d]);
  s += __shfl_xor(s, 1);
  s += __shfl_xor(s, 2);
  s += __shfl_xor(s, 4);
  if (kl == 0) bqp[j] = s * scale;
}

// ---- te table + te sums [proven R12] ----
__global__ __launch_bounds__(512) void te_k(const float* __restrict__ Wt,
                                            const float* __restrict__ bt,
                                            float* __restrict__ te,
                                            float* __restrict__ teSums) {
  __shared__ float emb[512];
  __shared__ float red[8];
  const int ci = blockIdx.x;
  const float t = 0.25f * (float)((ci >> 1) + (ci & 1));
  const int j = threadIdx.x;
  if (j < 256) {
    float fr = expf(-9.210340371976184f * (float)j * (1.0f / 255.0f));
    float ang = t * fr;
    emb[j] = sinf(ang);
    emb[j + 256] = cosf(ang);
  }
  __syncthreads();
  float s0 = 0.f, s1 = 0.f, s2 = 0.f, s3 = 0.f;
  for (int k = 0; k < 512; k += 4) {
    s0 += emb[k] * Wt[(size_t)k * 512 + j];
    s1 += emb[k + 1] * Wt[(size_t)(k + 1) * 512 + j];
    s2 += emb[k + 2] * Wt[(size_t)(k + 2) * 512 + j];
    s3 += emb[k + 3] * Wt[(size_t)(k + 3) * 512 + j];
  }
  float val = bt[j] + ((s0 + s1) + (s2 + s3));
  te[(size_t)ci * 512 + j] = val;
  float sv = val, sq = val * val;
#pragma unroll
  for (int o = 32; o > 0; o >>= 1) { sv += __shfl_xor(sv, o); sq += __shfl_xor(sq, o); }
  if ((j & 63) == 0) red[j >> 6] = sv;
  __syncthreads();
  if (j == 0) {
    float tot = 0.f;
    for (int i = 0; i < 8; ++i) tot += red[i];
    teSums[2 * ci] = tot;
  }
  __syncthreads();
  if ((j & 63) == 0) red[j >> 6] = sq;
  __syncthreads();
  if (j == 0) {
    float tot = 0.f;
    for (int i = 0; i < 8; ++i) tot += red[i];
    teSums[2 * ci + 1] = tot;
  }
}

// ---- factored attention [proven, verbatim] ----
__global__ __launch_bounds__(256) void attn_k(const __hip_bfloat16* __restrict__ hq,
                                              const short* __restrict__ lnsm,
                                              __hip_bfloat16* __restrict__ sctx) {
  const int b = blockIdx.x;
  const int tid = threadIdx.x;
  const int w = tid >> 6, l = tid & 63;
  __shared__ __align__(16) short smt[64 * 128];
  __shared__ float qs[512];
  __shared__ float att[4][64];
  {
    unsigned int u = ((const unsigned int*)(hq + (size_t)b * 1024 + 512))[tid];
    qs[2 * tid] = bflo(u);
    qs[2 * tid + 1] = bfhi(u);
  }
  {
    const int m = tid >> 2;
    const short* src = lnsm + ((size_t)b * 64 + m) * 128;
#pragma unroll
    for (int j = 0; j < 4; ++j) {
      int c = (tid & 3) + 4 * j;
      short8 v = *(const short8*)(src + c * 8);
      *(short8*)&smt[m * 128 + ((c ^ (m & 7)) * 8)] = v;
    }
  }
  __syncthreads();
  const float* qh = qs + w * 128;
  float acc = 0.f;
#pragma unroll
  for (int i = 0; i < 16; ++i) {
    uint4 u = *(const uint4*)&smt[l * 128 + ((i ^ (l & 7)) * 8)];
    const int d = i * 8;
    acc += bflo(u.x) * qh[d + 0] + bfhi(u.x) * qh[d + 1] +
           bflo(u.y) * qh[d + 2] + bfhi(u.y) * qh[d + 3] +
           bflo(u.z) * qh[d + 4] + bfhi(u.z) * qh[d + 5] +
           bflo(u.w) * qh[d + 6] + bfhi(u.w) * qh[d + 7];
  }
  float mx = acc;
#pragma unroll
  for (int o = 32; o > 0; o >>= 1) mx = fmaxf(mx, __shfl_xor(mx, o));
  float e = expf(acc - mx);
  float se = e;
#pragma unroll
  for (int o = 32; o > 0; o >>= 1) se += __shfl_xor(se, o);
  att[w][l] = e / se;
  const int cb = l >> 2, doff = 2 * (l & 3);
  float a0 = 0.f, a1 = 0.f;
#pragma unroll 8
  for (int m = 0; m < 64; ++m) {
    float am = att[w][m];
    unsigned int u = *(const unsigned int*)&smt[m * 128 + ((cb ^ (m & 7)) * 8) + doff];
    a0 += am * bflo(u);
    a1 += am * bfhi(u);
  }
  unsigned int pr = ((unsigned int)(unsigned short)bf16s(a1) << 16) |
                    (unsigned int)(unsigned short)bf16s(a0);
  ((unsigned int*)(sctx + (size_t)b * 512 + w * 128))[l] = pr;
}

extern "C" void kernel_launch(void* const* d_in, const int* in_sizes, int n_in,
                              void* d_out, int out_size, void* d_ws, size_t ws_size,
                              hipStream_t stream) {
  (void)in_sizes; (void)n_in; (void)out_size; (void)ws_size;
  const int B = 1024, Mm = 64;
  const int BMrows = B * Mm;  // 65536
  const float ATTN_SCALE = 0.08838834764831845f;  // 1/sqrt(128)
  const size_t SL = (size_t)512 * 512;

  const float* noise = (const float*)d_in[0];
  const float* context = (const float*)d_in[1];
  const float* sm = (const float*)d_in[2];
  // d_in[3] = num_steps == 4 (fixed; dt = 0.25)
  const float* mem_ln_g = (const float*)d_in[4];
  const float* mem_ln_b = (const float*)d_in[5];
  const float* Wa = (const float*)d_in[6];
  const float* ba = (const float*)d_in[7];
  const float* Wq = (const float*)d_in[8];
  const float* bq = (const float*)d_in[9];
  const float* Wk = (const float*)d_in[10];
  const float* bk = (const float*)d_in[11];
  (void)bk;  // K bias constant over m -> softmax-invariant, dropped exactly
  const float* Wv = (const float*)d_in[12];
  const float* bv = (const float*)d_in[13];
  const float* Wo = (const float*)d_in[14];
  const float* bo = (const float*)d_in[15];
  const float* pp_ln_g = (const float*)d_in[16];
  const float* pp_ln_b = (const float*)d_in[17];
  const float* Wp1 = (const float*)d_in[18];
  const float* bp1 = (const float*)d_in[19];
  const float* Wp2 = (const float*)d_in[20];
  const float* bp2 = (const float*)d_in[21];
  const float* Wc = (const float*)d_in[22];
  const float* bc = (const float*)d_in[23];
  const float* Wt = (const float*)d_in[24];
  const float* bt = (const float*)d_in[25];
  const float* f_ln_g = (const float*)d_in[26];
  const float* f_ln_b = (const float*)d_in[27];
  const float* Wf1 = (const float*)d_in[28];
  const float* bf1 = (const float*)d_in[29];
  const float* Wf2 = (const float*)d_in[30];
  const float* bf2 = (const float*)d_in[31];
  float* out = (float*)d_out;

  char* wsb = (char*)d_ws;
  size_t off = 0;
  auto alloc = [&](size_t bytes) -> void* {
    off = (off + 255) & ~(size_t)255;
    void* p = wsb + off;
    off += bytes;
    return p;
  };
  short* lnsm = (short*)alloc((size_t)BMrows * 128 * 2);  // 16.8 MB
  short* T512 = (short*)alloc(4 * SL * 2);
  short* WkT = T512;
  short* WvT = T512 + SL;
  short* WqT = T512 + 2 * SL;
  short* WoT = T512 + 3 * SL;
  short* Wp1T = (short*)alloc((size_t)512 * 128 * 2);
  short* WhqT = (short*)alloc((size_t)1024 * 512 * 2);  // [Wp2T | WqpT]
  short* WfoldT = (short*)alloc(SL * 2);
  short* WcT = (short*)alloc((size_t)512 * 256 * 2);
  short* WgT = (short*)alloc((size_t)512 * 2048 * 2);  // (g ⊙ Wf1)^T
  short* Wf2T = (short*)alloc((size_t)128 * 512 * 2);
  short* WaB = (short*)alloc((size_t)128 * 512 * 2);
  short* Wp2B = (short*)alloc(SL * 2);
  short* WakavB = (short*)alloc(2 * (size_t)128 * 512 * 2);
  short* Wak_bf = WakavB;
  short* Wav_bf = WakavB + (size_t)128 * 512;
  short* Wp2q_bf = (short*)alloc(SL * 2);
  float* bhq = (float*)alloc(1024 * 4);
  float* bofold = (float*)alloc(512 * 4);
  float* bhqq = (float*)alloc(512 * 4);
  float* bav = (float*)alloc(512 * 4);
  float* te_table = (float*)alloc(8 * 512 * 4);
  float* teWg = (float*)alloc(8 * 512 * 4);
  float* teSums = (float*)alloc(16 * 4);
  float* uvec = (float*)alloc(512 * 4);
  float* cbv = (float*)alloc(512 * 4);
  float* vpart = (float*)alloc((size_t)8 * 128 * 512 * 4);
  float* ctxWg = (float*)alloc((size_t)B * 512 * 4);
  float* ctxsums = (float*)alloc((size_t)B * 2 * 4);
  short* ctxh = (short*)alloc((size_t)B * 512 * 2);
  float* k1 = (float*)alloc((size_t)B * 128 * 4);
  float* ybuf = (float*)alloc((size_t)B * 128 * 4);
  short* ctxb = (short*)alloc((size_t)B * 256 * 2);
  short* yln = (short*)alloc((size_t)B * 128 * 2);
  short* hmid = (short*)alloc((size_t)B * 512 * 2);
  short* hqbuf = (short*)alloc((size_t)B * 1024 * 2);
  short* sctx = (short*)alloc((size_t)B * 512 * 2);
  short* mobuf = (short*)alloc((size_t)B * 512 * 2);
  short* fmid = (short*)alloc((size_t)B * 512 * 2);

  // ================= precompute (solver-invariant) [identical to R12] ========
  ln_bf16_k<<<BMrows / 4, 256, 0, stream>>>(sm, nullptr, 0.f, mem_ln_g, mem_ln_b,
                                            (__hip_bfloat16*)lnsm, BMrows);
  cast_bf16_k<<<(128 * 512 + 255) / 256, 256, 0, stream>>>(Wa, WaB, 128 * 512);
  cast_bf16_k<<<(512 * 512 + 255) / 256, 256, 0, stream>>>(Wp2, Wp2B, 512 * 512);
  cast_bf16_k<<<(B * 256 + 255) / 256, 256, 0, stream>>>(context, ctxb, B * 256);
  {
    TCBatch p;
    p.src[0] = Wk; p.src[1] = Wv; p.src[2] = Wq; p.src[3] = Wo; p.src[4] = Wp2;
    p.dst[0] = WkT; p.dst[1] = WvT; p.dst[2] = WqT; p.dst[3] = WoT; p.dst[4] = WhqT;
    transpose_cast_batch_k<<<dim3(8, 8, 5), 256, 0, stream>>>(p);
  }
  transpose_cast_k<<<dim3(8, 2), 256, 0, stream>>>(Wp1, Wp1T, 128, 512);
  transpose_cast_k<<<dim3(8, 4), 256, 0, stream>>>(Wc, WcT, 256, 512);
  transpose_cast_scale_k<<<dim3(8, 32), 256, 0, stream>>>(Wf1, f_ln_g, WgT, 2048, 512);
  transpose_cast_k<<<dim3(2, 8), 256, 0, stream>>>(Wf2, Wf2T, 512, 128);
  gemm_mfma_k<64, 64, false, true><<<dim3(8, 2, 2), 256, 0, stream>>>(
      WaB, WkT, nullptr, WakavB, 512, 512, 512, 512, 1.f, 0, (int)SL, 128 * 512);
  gemm_mfma_k<64, 64, false, true><<<dim3(8, 8), 256, 0, stream>>>(
      Wp2B, WqT, nullptr, Wp2q_bf, 512, 512, 512, 512, 1.f, 0, 0, 0);
  gemm_mfma_k<64, 64, false, true><<<dim3(8, 2, 4), 256, 0, stream>>>(
      Wak_bf, Wp2q_bf, nullptr, WhqT + SL, 128, 512, 512, 512, ATTN_SCALE,
      128, 128, 128 * 512);
  gemm_mfma_k<64, 64, false, true><<<dim3(2, 8, 4), 256, 0, stream>>>(
      WoT, Wav_bf, nullptr, WfoldT, 128, 512, 512, 512, 1.f, 128, 128, 128);
  vmp_k<<<dim3(32, 1, 1), 512, 0, stream>>>(bp2, nullptr, Wq, 0, 0, vpart);
  vmr_k<<<dim3(1, 1, 1), 512, 0, stream>>>(vpart, bq, 32, bhqq, 512);
  bqp_k<<<16, 256, 0, stream>>>(bhqq, Wak_bf, ATTN_SCALE, bhq + 512);
  hipMemcpyAsync(bhq, bp2, 512 * 4, hipMemcpyDeviceToDevice, stream);
  vmp_k<<<dim3(32, 1, 1), 512, 0, stream>>>(ba, nullptr, Wv, 0, 0, vpart);
  vmr_k<<<dim3(1, 1, 1), 512, 0, stream>>>(vpart, bv, 32, bav, 512);
  vmp_k<<<dim3(32, 1, 1), 512, 0, stream>>>(bav, nullptr, Wo, 0, 0, vpart);
  vmr_k<<<dim3(1, 1, 1), 512, 0, stream>>>(vpart, bo, 32, bofold, 512);
  gemm_mfma_k<64, 64, false, true><<<dim3(8, 16), 256, 0, stream>>>(
      ctxb, WcT, bc, ctxh, 256, 256, 256, 512, 1.f, 0, 0, 0);
  te_k<<<8, 512, 0, stream>>>(Wt, bt, te_table, teSums);
  vmp_k<<<dim3(128, 1, 1), 512, 0, stream>>>(f_ln_g, nullptr, Wf1, 0, 0, vpart);
  vmr_k<<<dim3(1, 1, 1), 512, 0, stream>>>(vpart, nullptr, 128, uvec, 512);
  vmp_k<<<dim3(128, 1, 1), 512, 0, stream>>>(f_ln_b, nullptr, Wf1, 0, 0, vpart);
  vmr_k<<<dim3(1, 1, 1), 512, 0, stream>>>(vpart, bf1, 128, cbv, 512);
  vmp_k<<<dim3(32, 1, 8), 512, 0, stream>>>(te_table, f_ln_g + 1536, Wf1, 1536, 512, vpart);
  vmr_k<<<dim3(1, 1, 8), 512, 0, stream>>>(vpart, nullptr, 32, teWg, 512);
  gemm_mfma_k<64, 64, false, false><<<dim3(8, 16), 256, 0, stream>>>(
      ctxh, WgT + 1024, nullptr, ctxWg, 512, 512, 2048, 512, 1.f, 0, 0, 0);
  rowsum_k<<<B / 4, 256, 0, stream>>>(ctxh, ctxsums, B);

  // ================= solver [R12 minus zstats dispatch] =================
  const float dt = 0.25f;
  auto chain = [&](const float* ycur, const float* kin, float a, int tidx) {
    ln_bf16_k<<<B / 4, 256, 0, stream>>>(ycur, kin, a, pp_ln_g, pp_ln_b,
                                         (__hip_bfloat16*)yln, B);
    gemm_mfma_k<32, 32, true, true><<<dim3(16, 32), 128, 0, stream>>>(
        yln, Wp1T, bp1, hmid, 128, 128, 128, 512, 1.f, 0, 0, 0);
    gemm_mfma_k<32, 64, false, true><<<dim3(16, 32), 128, 0, stream>>>(
        hmid, WhqT, bhq, hqbuf, 512, 512, 512, 1024, 1.f, 0, 0, 0);
    attn_k<<<B, 256, 0, stream>>>((const __hip_bfloat16*)hqbuf, lnsm,
                                  (__hip_bfloat16*)sctx);
    gemm_mfma_k<32, 32, false, true><<<dim3(16, 32), 128, 0, stream>>>(
        sctx, WfoldT, bofold, mobuf, 512, 512, 512, 512, 1.f, 0, 0, 0);
    // zgemm2 with in-kernel LN stats (pass-1) — replaces zstats + zgemm2
    zgemm2_k<<<dim3(16, 32), 128, 0, stream>>>(
        hqbuf, mobuf, ctxWg, teWg + (size_t)tidx * 512, uvec, cbv,
        ctxsums, teSums + 2 * tidx, WgT, fmid);
  };

  const float* ycur = noise;
  for (int s = 0; s < 4; ++s) {
    // eval 1: k1 = v(y, t0)
    chain(ycur, nullptr, 0.f, 2 * s);
    gemm_mfma_k<32, 32, false, false><<<dim3(4, 32), 128, 0, stream>>>(
        fmid, Wf2T, bf2, k1, 512, 512, 512, 128, 1.f, 0, 0, 0);
    // eval 2: LN(y + dt*k1) fused; ynext = y + dt/2*(k1 + v2)
    chain(ycur, k1, dt, 2 * s + 1);
    float* ynext = (s == 3) ? out : ybuf;
    gemm_heun_k<<<dim3(4, 16), 256, 0, stream>>>(
        fmid, Wf2T, bf2, ycur, k1, 0.5f * dt, ynext);
    ycur = ybuf;
  }
}

// Round 15
// 524.808 us; speedup vs baseline: 4.3083x; 1.1828x over previous
//
#include <hip/hip_runtime.h>
#include <hip/hip_bf16.h>
#include <cstdint>
#include <cstddef>

#define LN_EPS 1e-5f

typedef __attribute__((ext_vector_type(8))) short short8;
typedef __attribute__((ext_vector_type(4))) float f32x4;

__device__ __forceinline__ float gelu_exact(float x) {
  return 0.5f * x * (1.0f + erff(x * 0.70710678118654752440f));
}
__device__ __forceinline__ float bflo(unsigned int x) {
  union { unsigned int i; float f; } v; v.i = x << 16; return v.f;
}
__device__ __forceinline__ float bfhi(unsigned int x) {
  union { unsigned int i; float f; } v; v.i = x & 0xffff0000u; return v.f;
}
__device__ __forceinline__ float bf2f(short s) {
  union { unsigned int i; float f; } v; v.i = ((unsigned int)(unsigned short)s) << 16; return v.f;
}
__device__ __forceinline__ short bf16s(float f) {
  __hip_bfloat16 h = __float2bfloat16(f);
  return *reinterpret_cast<short*>(&h);
}

// ---- fused (y + a*k) -> LayerNorm(128) -> bf16 out  [proven] ----
__global__ __launch_bounds__(256) void ln_bf16_k(const float* __restrict__ X,
                                                 const float* __restrict__ KIN, float a,
                                                 const float* __restrict__ g,
                                                 const float* __restrict__ bb,
                                                 __hip_bfloat16* __restrict__ out, int rows) {
  int row = blockIdx.x * 4 + (threadIdx.x >> 6);
  if (row >= rows) return;
  int l = threadIdx.x & 63;
  size_t base = (size_t)row * 128;
  float x0 = X[base + l], x1 = X[base + l + 64];
  if (KIN) { x0 += a * KIN[base + l]; x1 += a * KIN[base + l + 64]; }
  float s = x0 + x1;
#pragma unroll
  for (int o = 32; o > 0; o >>= 1) s += __shfl_xor(s, o);
  float mu = s * (1.0f / 128.0f);
  float d0 = x0 - mu, d1 = x1 - mu;
  float v = d0 * d0 + d1 * d1;
#pragma unroll
  for (int o = 32; o > 0; o >>= 1) v += __shfl_xor(v, o);
  float rstd = rsqrtf(v * (1.0f / 128.0f) + LN_EPS);
  out[base + l] = __float2bfloat16(d0 * rstd * g[l] + bb[l]);
  out[base + l + 64] = __float2bfloat16(d1 * rstd * g[l + 64] + bb[l + 64]);
}

// ---- MFMA GEMM, BK=64, double-buffered LDS [proven] ----
template <int ROWS, int BN, bool GELU_OUT, bool OUT_BF16>
__global__ __launch_bounds__(ROWS * 4) void gemm_mfma_k(
    const short* __restrict__ A, const short* __restrict__ WT,
    const float* __restrict__ bias, void* __restrict__ Cout,
    int K, int lda, int ldw, int ldc, float alpha,
    int hsA, int hsB, long hsC) {
  constexpr int T = ROWS * 4;
  constexpr int NFRAG = BN / 16;
  constexpr int NB = (BN * 8) / T;
  __shared__ __align__(16) short As[2][ROWS][72];
  __shared__ __align__(16) short Bs[2][BN][72];
  A += (size_t)blockIdx.z * hsA;
  WT += (size_t)blockIdx.z * hsB;
  const size_t cOff = (size_t)blockIdx.z * (size_t)hsC;
  const int tid = threadIdx.x;
  const int w = tid >> 6, l = tid & 63;
  const int row0 = blockIdx.y * ROWS, col0 = blockIdx.x * BN;
  f32x4 acc[NFRAG];
#pragma unroll
  for (int i = 0; i < NFRAG; ++i) acc[i] = (f32x4){0.f, 0.f, 0.f, 0.f};

  const int nt = K >> 6;
  short8 aR0, aR1;
  short8 bR[NB];
  auto loadA = [&](int t) {
    int k0 = t * 64;
    int c1 = tid + T;
    aR0 = *(const short8*)(A + (size_t)(row0 + (tid >> 3)) * lda + k0 + (tid & 7) * 8);
    aR1 = *(const short8*)(A + (size_t)(row0 + (c1 >> 3)) * lda + k0 + (c1 & 7) * 8);
  };
  auto loadB = [&](int t) {
    int k0 = t * 64;
#pragma unroll
    for (int i = 0; i < NB; ++i) {
      int c = tid + i * T;
      bR[i] = *(const short8*)(WT + (size_t)(col0 + (c >> 3)) * ldw + k0 + (c & 7) * 8);
    }
  };
  auto storeT = [&](int buf) {
    int c1 = tid + T;
    *(short8*)&As[buf][tid >> 3][(tid & 7) * 8] = aR0;
    *(short8*)&As[buf][c1 >> 3][(c1 & 7) * 8] = aR1;
#pragma unroll
    for (int i = 0; i < NB; ++i) {
      int c = tid + i * T;
      *(short8*)&Bs[buf][c >> 3][(c & 7) * 8] = bR[i];
    }
  };

  loadA(0);
  loadB(0);
  for (int t = 0; t < nt; ++t) {
    int buf = t & 1;
    storeT(buf);
    __syncthreads();
    if (t + 1 < nt) { loadA(t + 1); loadB(t + 1); }
    short8 af0 = *(const short8*)&As[buf][w * 16 + (l & 15)][(l >> 4) * 8];
    short8 af1 = *(const short8*)&As[buf][w * 16 + (l & 15)][(l >> 4) * 8 + 32];
#pragma unroll
    for (int nc = 0; nc < NFRAG; ++nc) {
      short8 bf0 = *(const short8*)&Bs[buf][nc * 16 + (l & 15)][(l >> 4) * 8];
      acc[nc] = __builtin_amdgcn_mfma_f32_16x16x32_bf16(af0, bf0, acc[nc], 0, 0, 0);
      short8 bf1 = *(const short8*)&Bs[buf][nc * 16 + (l & 15)][(l >> 4) * 8 + 32];
      acc[nc] = __builtin_amdgcn_mfma_f32_16x16x32_bf16(af1, bf1, acc[nc], 0, 0, 0);
    }
    __syncthreads();
  }
  const int cr = (l >> 4) * 4;
  const int cc = l & 15;
#pragma unroll
  for (int nc = 0; nc < NFRAG; ++nc) {
    int gc = col0 + nc * 16 + cc;
    float bv = bias ? bias[gc] : 0.0f;
#pragma unroll
    for (int r = 0; r < 4; ++r) {
      int gr = row0 + w * 16 + cr + r;
      float v = acc[nc][r] * alpha + bv;
      if (GELU_OUT) v = gelu_exact(v);
      if (OUT_BF16)
        ((__hip_bfloat16*)Cout)[cOff + (size_t)gr * ldc + gc] = __float2bfloat16(v);
      else
        ((float*)Cout)[cOff + (size_t)gr * ldc + gc] = v;
    }
  }
}

// ---- [h|mo] @ Wg_hm with LN folded into f32 epilogue [proven R12] ----
__global__ __launch_bounds__(128) void zgemm2_k(
    const short* __restrict__ hq, const short* __restrict__ mo,
    const float* __restrict__ ctxWg, const float* __restrict__ teWgRow,
    const float* __restrict__ u, const float* __restrict__ cbv,
    const float* __restrict__ murs, const short* __restrict__ WgT,
    short* __restrict__ outC) {
  __shared__ __align__(16) short As[2][32][72];
  __shared__ __align__(16) short Bs[2][32][72];
  const int tid = threadIdx.x;
  const int w = tid >> 6, l = tid & 63;
  const int row0 = blockIdx.y * 32, col0 = blockIdx.x * 32;
  const int rA0 = tid >> 3, rA1 = rA0 + 16, kc = (tid & 7) * 8;
  f32x4 acc[2];
  acc[0] = (f32x4){0.f, 0.f, 0.f, 0.f};
  acc[1] = (f32x4){0.f, 0.f, 0.f, 0.f};
  short8 aR0, aR1;
  short8 bR[2];
  auto loadA = [&](int t) {
    const int k = t * 64 + kc;
    const short* src;
    int stride, koff;
    if (k < 512) { src = hq; stride = 1024; koff = k; }
    else         { src = mo; stride = 512;  koff = k - 512; }
    aR0 = *(const short8*)(src + (size_t)(row0 + rA0) * stride + koff);
    aR1 = *(const short8*)(src + (size_t)(row0 + rA1) * stride + koff);
  };
  auto loadB = [&](int t) {
    int k0 = t * 64;
#pragma unroll
    for (int i = 0; i < 2; ++i) {
      int c = tid + i * 128;
      bR[i] = *(const short8*)(WgT + (size_t)(col0 + (c >> 3)) * 2048 + k0 + (c & 7) * 8);
    }
  };
  auto storeT = [&](int buf) {
    *(short8*)&As[buf][rA0][kc] = aR0;
    *(short8*)&As[buf][rA1][kc] = aR1;
#pragma unroll
    for (int i = 0; i < 2; ++i) {
      int c = tid + i * 128;
      *(short8*)&Bs[buf][c >> 3][(c & 7) * 8] = bR[i];
    }
  };

  loadA(0);
  loadB(0);
  for (int t = 0; t < 16; ++t) {
    int buf = t & 1;
    storeT(buf);
    __syncthreads();
    if (t + 1 < 16) { loadA(t + 1); loadB(t + 1); }
    short8 af0 = *(const short8*)&As[buf][w * 16 + (l & 15)][(l >> 4) * 8];
    short8 af1 = *(const short8*)&As[buf][w * 16 + (l & 15)][(l >> 4) * 8 + 32];
#pragma unroll
    for (int nc = 0; nc < 2; ++nc) {
      short8 bf0 = *(const short8*)&Bs[buf][nc * 16 + (l & 15)][(l >> 4) * 8];
      acc[nc] = __builtin_amdgcn_mfma_f32_16x16x32_bf16(af0, bf0, acc[nc], 0, 0, 0);
      short8 bf1 = *(const short8*)&Bs[buf][nc * 16 + (l & 15)][(l >> 4) * 8 + 32];
      acc[nc] = __builtin_amdgcn_mfma_f32_16x16x32_bf16(af1, bf1, acc[nc], 0, 0, 0);
    }
    __syncthreads();
  }
  const int cr = (l >> 4) * 4, cc = l & 15;
#pragma unroll
  for (int nc = 0; nc < 2; ++nc) {
    int gc = col0 + nc * 16 + cc;
    float uu = u[gc], cb = cbv[gc], tw = teWgRow[gc];
#pragma unroll
    for (int r = 0; r < 4; ++r) {
      int gr = row0 + w * 16 + cr + r;
      float mu = murs[2 * gr], rs = murs[2 * gr + 1];
      float v = rs * (acc[nc][r] + ctxWg[(size_t)gr * 512 + gc] + tw - mu * uu) + cb;
      outC[(size_t)gr * 512 + gc] = bf16s(gelu_exact(v));
    }
  }
}

// ---- per-row LN(2048) stats [proven R12] ----
__global__ __launch_bounds__(256) void zstats_k(const short* __restrict__ hq,
                                                const short* __restrict__ mo,
                                                const float* __restrict__ ctxsums,
                                                const float* __restrict__ teSums2,
                                                float* __restrict__ murs, int rows) {
  int row = blockIdx.x * 4 + (threadIdx.x >> 6);
  if (row >= rows) return;
  int l = threadIdx.x & 63;
  short8 hv = *(const short8*)(hq + (size_t)row * 1024 + l * 8);
  short8 mv = *(const short8*)(mo + (size_t)row * 512 + l * 8);
  float s = 0.f, s2 = 0.f;
#pragma unroll
  for (int j = 0; j < 8; ++j) {
    float fa = bf2f(hv[j]), fb = bf2f(mv[j]);
    s += fa + fb;
    s2 += fa * fa + fb * fb;
  }
#pragma unroll
  for (int o = 32; o > 0; o >>= 1) { s += __shfl_xor(s, o); s2 += __shfl_xor(s2, o); }
  if (l == 0) {
    float S = s + ctxsums[2 * row] + teSums2[0];
    float S2 = s2 + ctxsums[2 * row + 1] + teSums2[1];
    float mu = S * (1.0f / 2048.0f);
    murs[2 * row] = mu;
    murs[2 * row + 1] = rsqrtf(S2 * (1.0f / 2048.0f) - mu * mu + LN_EPS);
  }
}

// ---- per-row sum/sumsq of (rows x 512) bf16 [proven] ----
__global__ __launch_bounds__(256) void rowsum_k(const short* __restrict__ X,
                                                float* __restrict__ sums, int rows) {
  int row = blockIdx.x * 4 + (threadIdx.x >> 6);
  if (row >= rows) return;
  int l = threadIdx.x & 63;
  short8 v = *(const short8*)(X + (size_t)row * 512 + l * 8);
  float s = 0.f, s2 = 0.f;
#pragma unroll
  for (int j = 0; j < 8; ++j) { float f = bf2f(v[j]); s += f; s2 += f * f; }
#pragma unroll
  for (int o = 32; o > 0; o >>= 1) { s += __shfl_xor(s, o); s2 += __shfl_xor(s2, o); }
  if (l == 0) { sums[2 * row] = s; sums[2 * row + 1] = s2; }
}

// ---- coalesced vec@mat stage 1 [proven R12] ----
__global__ __launch_bounds__(512) void vmp_k(const float* __restrict__ va,
                                             const float* __restrict__ vb,
                                             const float* __restrict__ W,
                                             int woff, int hsA,
                                             float* __restrict__ part) {
  const int j = threadIdx.x;
  const int b = blockIdx.x, z = blockIdx.z;
  const float* vaz = va + (size_t)z * hsA;
  float s = 0.f;
#pragma unroll 4
  for (int i = 0; i < 16; ++i) {
    int k = b * 16 + i;
    float c = vaz[k];
    if (vb) c *= vb[k];
    s += c * W[(size_t)(woff + k) * 512 + j];
  }
  part[((size_t)z * gridDim.x + b) * 512 + j] = s;
}

// ---- vec@mat stage 2 [proven R12] ----
__global__ __launch_bounds__(512) void vmr_k(const float* __restrict__ part,
                                             const float* __restrict__ base, int KB,
                                             float* __restrict__ out, int hsOut) {
  const int j = threadIdx.x;
  const int z = blockIdx.z;
  float s = base ? base[j] : 0.f;
  for (int b = 0; b < KB; ++b) s += part[((size_t)z * KB + b) * 512 + j];
  out[(size_t)z * hsOut + j] = s;
}

// ---- R15: batched independent vec@mat folds (same math as vmp_k/vmr_k) ----
struct VMB4 {
  const float* va[4]; const float* vb[4]; const float* W[4];
  int woff[4]; int KB[4];
  const float* base[4]; float* out[4];
};
__global__ __launch_bounds__(512) void vmp_b4_k(VMB4 p, float* __restrict__ part) {
  const int z = blockIdx.z;
  const int b = blockIdx.x;
  if (b >= p.KB[z]) return;
  const int j = threadIdx.x;
  const float* va = p.va[z];
  const float* vb = p.vb[z];
  const float* W = p.W[z];
  const int woff = p.woff[z];
  float s = 0.f;
#pragma unroll 4
  for (int i = 0; i < 16; ++i) {
    int k = b * 16 + i;
    float c = va[k];
    if (vb) c *= vb[k];
    s += c * W[(size_t)(woff + k) * 512 + j];
  }
  part[((size_t)z * 128 + b) * 512 + j] = s;
}
__global__ __launch_bounds__(512) void vmr_b4_k(VMB4 p, const float* __restrict__ part) {
  const int z = blockIdx.z;
  const int j = threadIdx.x;
  const float* base = p.base[z];
  float s = base ? base[j] : 0.f;
  const int KB = p.KB[z];
  for (int b = 0; b < KB; ++b) s += part[((size_t)z * 128 + b) * 512 + j];
  p.out[z][j] = s;
}

// ---- R15: 9-way batched transpose+cast (optional per-row scale).
// Body identical to proven transpose_cast_scale_k; out-of-range tiles exit.
struct TCB9 {
  const float* src[9]; short* dst[9]; const float* scale[9];
  int K[9]; int N[9];
};
__global__ __launch_bounds__(256) void transpose_cast_b9_k(TCB9 p) {
  const int z = blockIdx.z;
  const int K = p.K[z], N = p.N[z];
  int n0 = blockIdx.x * 64, k0 = blockIdx.y * 64;
  if (n0 >= N || k0 >= K) return;
  const float* W = p.src[z];
  short* WT = p.dst[z];
  const float* scale = p.scale[z];
  __shared__ float tile[64][65];
#pragma unroll
  for (int i = 0; i < 16; ++i) {
    int e = threadIdx.x + i * 256;
    int r = e >> 6, c = e & 63;
    float v = W[(size_t)(k0 + r) * N + n0 + c];
    if (scale) v *= scale[k0 + r];
    tile[r][c] = v;
  }
  __syncthreads();
#pragma unroll
  for (int i = 0; i < 16; ++i) {
    int e = threadIdx.x + i * 256;
    int r = e >> 6, c = e & 63;
    WT[(size_t)(n0 + r) * K + k0 + c] = bf16s(tile[c][r]);
  }
}

// ---- R15: 3-segment cast f32 -> bf16 ----
struct C3 { const float* src[3]; short* dst[3]; int n[3]; };
__global__ void cast3_k(C3 p) {
  const int z = blockIdx.z;
  int i = blockIdx.x * blockDim.x + threadIdx.x;
  if (i < p.n[z]) p.dst[z][i] = bf16s(p.src[z][i]);
}

// ---- GEMM (Wf2) + Heun epilogue [proven] ----
__global__ __launch_bounds__(256) void gemm_heun_k(
    const short* __restrict__ A, const short* __restrict__ WT,
    const float* __restrict__ bias, const float* __restrict__ yin,
    const float* __restrict__ kaux, float c0, float* __restrict__ outY) {
  __shared__ __align__(16) short As[2][64][72];
  __shared__ __align__(16) short Bs[2][32][72];
  const int tid = threadIdx.x;
  const int w = tid >> 6, l = tid & 63;
  const int row0 = blockIdx.y * 64, col0 = blockIdx.x * 32;
  f32x4 acc[2];
  acc[0] = (f32x4){0.f, 0.f, 0.f, 0.f};
  acc[1] = (f32x4){0.f, 0.f, 0.f, 0.f};
  short8 aR0, aR1, bR;
  auto loadA = [&](int t) {
    int k0 = t * 64;
    int c1 = tid + 256;
    aR0 = *(const short8*)(A + (size_t)(row0 + (tid >> 3)) * 512 + k0 + (tid & 7) * 8);
    aR1 = *(const short8*)(A + (size_t)(row0 + (c1 >> 3)) * 512 + k0 + (c1 & 7) * 8);
  };
  auto loadB = [&](int t) {
    int k0 = t * 64;
    bR = *(const short8*)(WT + (size_t)(col0 + (tid >> 3)) * 512 + k0 + (tid & 7) * 8);
  };
  auto storeT = [&](int buf) {
    int c1 = tid + 256;
    *(short8*)&As[buf][tid >> 3][(tid & 7) * 8] = aR0;
    *(short8*)&As[buf][c1 >> 3][(c1 & 7) * 8] = aR1;
    *(short8*)&Bs[buf][tid >> 3][(tid & 7) * 8] = bR;
  };
  loadA(0);
  loadB(0);
  for (int t = 0; t < 8; ++t) {
    int buf = t & 1;
    storeT(buf);
    __syncthreads();
    if (t + 1 < 8) { loadA(t + 1); loadB(t + 1); }
    short8 af0 = *(const short8*)&As[buf][w * 16 + (l & 15)][(l >> 4) * 8];
    short8 af1 = *(const short8*)&As[buf][w * 16 + (l & 15)][(l >> 4) * 8 + 32];
#pragma unroll
    for (int nc = 0; nc < 2; ++nc) {
      short8 bf0 = *(const short8*)&Bs[buf][nc * 16 + (l & 15)][(l >> 4) * 8];
      acc[nc] = __builtin_amdgcn_mfma_f32_16x16x32_bf16(af0, bf0, acc[nc], 0, 0, 0);
      short8 bf1 = *(const short8*)&Bs[buf][nc * 16 + (l & 15)][(l >> 4) * 8 + 32];
      acc[nc] = __builtin_amdgcn_mfma_f32_16x16x32_bf16(af1, bf1, acc[nc], 0, 0, 0);
    }
    __syncthreads();
  }
  const int cr = (l >> 4) * 4, cc = l & 15;
#pragma unroll
  for (int nc = 0; nc < 2; ++nc) {
    int gc = col0 + nc * 16 + cc;
    float bv = bias[gc];
#pragma unroll
    for (int r = 0; r < 4; ++r) {
      int gr = row0 + w * 16 + cr + r;
      float v = acc[nc][r] + bv;
      size_t idx = (size_t)gr * 128 + gc;
      outY[idx] = yin[idx] + c0 * (kaux[idx] + v);
    }
  }
}

// ---- bqp [proven; small K=128] ----
__global__ __launch_bounds__(256) void bqp_k(const float* __restrict__ bhqq,
                                             const short* __restrict__ Wak_bf,
                                             float scale, float* __restrict__ bqp) {
  const int tid = threadIdx.x;
  const int j = blockIdx.x * 32 + (tid >> 3);
  const int h = j >> 7, e = j & 127;
  const int kl = tid & 7;
  float s = 0.f;
  for (int d = kl; d < 128; d += 8)
    s += bhqq[h * 128 + d] * bf2f(Wak_bf[(size_t)e * 512 + h * 128 + d]);
  s += __shfl_xor(s, 1);
  s += __shfl_xor(s, 2);
  s += __shfl_xor(s, 4);
  if (kl == 0) bqp[j] = s * scale;
}

// ---- te table + te sums [proven R12] ----
__global__ __launch_bounds__(512) void te_k(const float* __restrict__ Wt,
                                            const float* __restrict__ bt,
                                            float* __restrict__ te,
                                            float* __restrict__ teSums) {
  __shared__ float emb[512];
  __shared__ float red[8];
  const int ci = blockIdx.x;
  const float t = 0.25f * (float)((ci >> 1) + (ci & 1));
  const int j = threadIdx.x;
  if (j < 256) {
    float fr = expf(-9.210340371976184f * (float)j * (1.0f / 255.0f));
    float ang = t * fr;
    emb[j] = sinf(ang);
    emb[j + 256] = cosf(ang);
  }
  __syncthreads();
  float s0 = 0.f, s1 = 0.f, s2 = 0.f, s3 = 0.f;
  for (int k = 0; k < 512; k += 4) {
    s0 += emb[k] * Wt[(size_t)k * 512 + j];
    s1 += emb[k + 1] * Wt[(size_t)(k + 1) * 512 + j];
    s2 += emb[k + 2] * Wt[(size_t)(k + 2) * 512 + j];
    s3 += emb[k + 3] * Wt[(size_t)(k + 3) * 512 + j];
  }
  float val = bt[j] + ((s0 + s1) + (s2 + s3));
  te[(size_t)ci * 512 + j] = val;
  float sv = val, sq = val * val;
#pragma unroll
  for (int o = 32; o > 0; o >>= 1) { sv += __shfl_xor(sv, o); sq += __shfl_xor(sq, o); }
  if ((j & 63) == 0) red[j >> 6] = sv;
  __syncthreads();
  if (j == 0) {
    float tot = 0.f;
    for (int i = 0; i < 8; ++i) tot += red[i];
    teSums[2 * ci] = tot;
  }
  __syncthreads();
  if ((j & 63) == 0) red[j >> 6] = sq;
  __syncthreads();
  if (j == 0) {
    float tot = 0.f;
    for (int i = 0; i < 8; ++i) tot += red[i];
    teSums[2 * ci + 1] = tot;
  }
}

// ---- factored attention [proven, verbatim] ----
__global__ __launch_bounds__(256) void attn_k(const __hip_bfloat16* __restrict__ hq,
                                              const short* __restrict__ lnsm,
                                              __hip_bfloat16* __restrict__ sctx) {
  const int b = blockIdx.x;
  const int tid = threadIdx.x;
  const int w = tid >> 6, l = tid & 63;
  __shared__ __align__(16) short smt[64 * 128];
  __shared__ float qs[512];
  __shared__ float att[4][64];
  {
    unsigned int u = ((const unsigned int*)(hq + (size_t)b * 1024 + 512))[tid];
    qs[2 * tid] = bflo(u);
    qs[2 * tid + 1] = bfhi(u);
  }
  {
    const int m = tid >> 2;
    const short* src = lnsm + ((size_t)b * 64 + m) * 128;
#pragma unroll
    for (int j = 0; j < 4; ++j) {
      int c = (tid & 3) + 4 * j;
      short8 v = *(const short8*)(src + c * 8);
      *(short8*)&smt[m * 128 + ((c ^ (m & 7)) * 8)] = v;
    }
  }
  __syncthreads();
  const float* qh = qs + w * 128;
  float acc = 0.f;
#pragma unroll
  for (int i = 0; i < 16; ++i) {
    uint4 u = *(const uint4*)&smt[l * 128 + ((i ^ (l & 7)) * 8)];
    const int d = i * 8;
    acc += bflo(u.x) * qh[d + 0] + bfhi(u.x) * qh[d + 1] +
           bflo(u.y) * qh[d + 2] + bfhi(u.y) * qh[d + 3] +
           bflo(u.z) * qh[d + 4] + bfhi(u.z) * qh[d + 5] +
           bflo(u.w) * qh[d + 6] + bfhi(u.w) * qh[d + 7];
  }
  float mx = acc;
#pragma unroll
  for (int o = 32; o > 0; o >>= 1) mx = fmaxf(mx, __shfl_xor(mx, o));
  float e = expf(acc - mx);
  float se = e;
#pragma unroll
  for (int o = 32; o > 0; o >>= 1) se += __shfl_xor(se, o);
  att[w][l] = e / se;
  const int cb = l >> 2, doff = 2 * (l & 3);
  float a0 = 0.f, a1 = 0.f;
#pragma unroll 8
  for (int m = 0; m < 64; ++m) {
    float am = att[w][m];
    unsigned int u = *(const unsigned int*)&smt[m * 128 + ((cb ^ (m & 7)) * 8) + doff];
    a0 += am * bflo(u);
    a1 += am * bfhi(u);
  }
  unsigned int pr = ((unsigned int)(unsigned short)bf16s(a1) << 16) |
                    (unsigned int)(unsigned short)bf16s(a0);
  ((unsigned int*)(sctx + (size_t)b * 512 + w * 128))[l] = pr;
}

extern "C" void kernel_launch(void* const* d_in, const int* in_sizes, int n_in,
                              void* d_out, int out_size, void* d_ws, size_t ws_size,
                              hipStream_t stream) {
  (void)in_sizes; (void)n_in; (void)out_size; (void)ws_size;
  const int B = 1024, Mm = 64;
  const int BMrows = B * Mm;  // 65536
  const float ATTN_SCALE = 0.08838834764831845f;  // 1/sqrt(128)
  const size_t SL = (size_t)512 * 512;

  const float* noise = (const float*)d_in[0];
  const float* context = (const float*)d_in[1];
  const float* sm = (const float*)d_in[2];
  // d_in[3] = num_steps == 4 (fixed; dt = 0.25)
  const float* mem_ln_g = (const float*)d_in[4];
  const float* mem_ln_b = (const float*)d_in[5];
  const float* Wa = (const float*)d_in[6];
  const float* ba = (const float*)d_in[7];
  const float* Wq = (const float*)d_in[8];
  const float* bq = (const float*)d_in[9];
  const float* Wk = (const float*)d_in[10];
  const float* bk = (const float*)d_in[11];
  (void)bk;  // K bias constant over m -> softmax-invariant, dropped exactly
  const float* Wv = (const float*)d_in[12];
  const float* bv = (const float*)d_in[13];
  const float* Wo = (const float*)d_in[14];
  const float* bo = (const float*)d_in[15];
  const float* pp_ln_g = (const float*)d_in[16];
  const float* pp_ln_b = (const float*)d_in[17];
  const float* Wp1 = (const float*)d_in[18];
  const float* bp1 = (const float*)d_in[19];
  const float* Wp2 = (const float*)d_in[20];
  const float* bp2 = (const float*)d_in[21];
  const float* Wc = (const float*)d_in[22];
  const float* bc = (const float*)d_in[23];
  const float* Wt = (const float*)d_in[24];
  const float* bt = (const float*)d_in[25];
  const float* f_ln_g = (const float*)d_in[26];
  const float* f_ln_b = (const float*)d_in[27];
  const float* Wf1 = (const float*)d_in[28];
  const float* bf1 = (const float*)d_in[29];
  const float* Wf2 = (const float*)d_in[30];
  const float* bf2 = (const float*)d_in[31];
  float* out = (float*)d_out;

  char* wsb = (char*)d_ws;
  size_t off = 0;
  auto alloc = [&](size_t bytes) -> void* {
    off = (off + 255) & ~(size_t)255;
    void* p = wsb + off;
    off += bytes;
    return p;
  };
  short* lnsm = (short*)alloc((size_t)BMrows * 128 * 2);  // 16.8 MB
  short* T512 = (short*)alloc(4 * SL * 2);
  short* WkT = T512;
  short* WvT = T512 + SL;
  short* WqT = T512 + 2 * SL;
  short* WoT = T512 + 3 * SL;
  short* Wp1T = (short*)alloc((size_t)512 * 128 * 2);
  short* WhqT = (short*)alloc((size_t)1024 * 512 * 2);  // [Wp2T | WqpT]
  short* WfoldT = (short*)alloc(SL * 2);
  short* WcT = (short*)alloc((size_t)512 * 256 * 2);
  short* WgT = (short*)alloc((size_t)512 * 2048 * 2);  // (g ⊙ Wf1)^T
  short* Wf2T = (short*)alloc((size_t)128 * 512 * 2);
  short* WaB = (short*)alloc((size_t)128 * 512 * 2);
  short* Wp2B = (short*)alloc(SL * 2);
  short* WakavB = (short*)alloc(2 * (size_t)128 * 512 * 2);
  short* Wak_bf = WakavB;
  short* Wav_bf = WakavB + (size_t)128 * 512;
  short* Wp2q_bf = (short*)alloc(SL * 2);
  float* bhq = (float*)alloc(1024 * 4);
  float* bofold = (float*)alloc(512 * 4);
  float* bhqq = (float*)alloc(512 * 4);
  float* bav = (float*)alloc(512 * 4);
  float* te_table = (float*)alloc(8 * 512 * 4);
  float* teWg = (float*)alloc(8 * 512 * 4);
  float* teSums = (float*)alloc(16 * 4);
  float* uvec = (float*)alloc(512 * 4);
  float* cbv = (float*)alloc(512 * 4);
  float* vpart = (float*)alloc((size_t)8 * 128 * 512 * 4);
  float* ctxWg = (float*)alloc((size_t)B * 512 * 4);
  float* ctxsums = (float*)alloc((size_t)B * 2 * 4);
  float* murs = (float*)alloc((size_t)B * 2 * 4);
  short* ctxh = (short*)alloc((size_t)B * 512 * 2);
  float* k1 = (float*)alloc((size_t)B * 128 * 4);
  float* ybuf = (float*)alloc((size_t)B * 128 * 4);
  short* ctxb = (short*)alloc((size_t)B * 256 * 2);
  short* yln = (short*)alloc((size_t)B * 128 * 2);
  short* hmid = (short*)alloc((size_t)B * 512 * 2);
  short* hqbuf = (short*)alloc((size_t)B * 1024 * 2);
  short* sctx = (short*)alloc((size_t)B * 512 * 2);
  short* mobuf = (short*)alloc((size_t)B * 512 * 2);
  short* fmid = (short*)alloc((size_t)B * 512 * 2);

  // ================= precompute (solver-invariant; R15 batched) ==============
  ln_bf16_k<<<BMrows / 4, 256, 0, stream>>>(sm, nullptr, 0.f, mem_ln_g, mem_ln_b,
                                            (__hip_bfloat16*)lnsm, BMrows);
  {
    C3 c;
    c.src[0] = Wa;        c.dst[0] = WaB;  c.n[0] = 128 * 512;
    c.src[1] = Wp2;       c.dst[1] = Wp2B; c.n[1] = 512 * 512;
    c.src[2] = context;   c.dst[2] = ctxb; c.n[2] = B * 256;
    cast3_k<<<dim3(1024, 1, 3), 256, 0, stream>>>(c);
  }
  {
    TCB9 p;
    p.src[0] = Wk;  p.dst[0] = WkT;  p.scale[0] = nullptr; p.K[0] = 512;  p.N[0] = 512;
    p.src[1] = Wv;  p.dst[1] = WvT;  p.scale[1] = nullptr; p.K[1] = 512;  p.N[1] = 512;
    p.src[2] = Wq;  p.dst[2] = WqT;  p.scale[2] = nullptr; p.K[2] = 512;  p.N[2] = 512;
    p.src[3] = Wo;  p.dst[3] = WoT;  p.scale[3] = nullptr; p.K[3] = 512;  p.N[3] = 512;
    p.src[4] = Wp2; p.dst[4] = WhqT; p.scale[4] = nullptr; p.K[4] = 512;  p.N[4] = 512;
    p.src[5] = Wp1; p.dst[5] = Wp1T; p.scale[5] = nullptr; p.K[5] = 128;  p.N[5] = 512;
    p.src[6] = Wc;  p.dst[6] = WcT;  p.scale[6] = nullptr; p.K[6] = 256;  p.N[6] = 512;
    p.src[7] = Wf1; p.dst[7] = WgT;  p.scale[7] = f_ln_g;  p.K[7] = 2048; p.N[7] = 512;
    p.src[8] = Wf2; p.dst[8] = Wf2T; p.scale[8] = nullptr; p.K[8] = 512;  p.N[8] = 128;
    transpose_cast_b9_k<<<dim3(8, 32, 9), 256, 0, stream>>>(p);
  }
  gemm_mfma_k<64, 64, false, true><<<dim3(8, 2, 2), 256, 0, stream>>>(
      WaB, WkT, nullptr, WakavB, 512, 512, 512, 512, 1.f, 0, (int)SL, 128 * 512);
  gemm_mfma_k<64, 64, false, true><<<dim3(8, 8), 256, 0, stream>>>(
      Wp2B, WqT, nullptr, Wp2q_bf, 512, 512, 512, 512, 1.f, 0, 0, 0);
  gemm_mfma_k<64, 64, false, true><<<dim3(8, 2, 4), 256, 0, stream>>>(
      Wak_bf, Wp2q_bf, nullptr, WhqT + SL, 128, 512, 512, 512, ATTN_SCALE,
      128, 128, 128 * 512);
  gemm_mfma_k<64, 64, false, true><<<dim3(2, 8, 4), 256, 0, stream>>>(
      WoT, Wav_bf, nullptr, WfoldT, 128, 512, 512, 512, 1.f, 128, 128, 128);
  // batched independent vec@mat folds: bhqq, bav, uvec, cbv
  {
    VMB4 p;
    p.va[0] = bp2;     p.vb[0] = nullptr; p.W[0] = Wq;  p.woff[0] = 0; p.KB[0] = 32;
    p.base[0] = bq;    p.out[0] = bhqq;
    p.va[1] = ba;      p.vb[1] = nullptr; p.W[1] = Wv;  p.woff[1] = 0; p.KB[1] = 32;
    p.base[1] = bv;    p.out[1] = bav;
    p.va[2] = f_ln_g;  p.vb[2] = nullptr; p.W[2] = Wf1; p.woff[2] = 0; p.KB[2] = 128;
    p.base[2] = nullptr; p.out[2] = uvec;
    p.va[3] = f_ln_b;  p.vb[3] = nullptr; p.W[3] = Wf1; p.woff[3] = 0; p.KB[3] = 128;
    p.base[3] = bf1;   p.out[3] = cbv;
    vmp_b4_k<<<dim3(128, 1, 4), 512, 0, stream>>>(p, vpart);
    vmr_b4_k<<<dim3(1, 1, 4), 512, 0, stream>>>(p, vpart);
  }
  bqp_k<<<16, 256, 0, stream>>>(bhqq, Wak_bf, ATTN_SCALE, bhq + 512);
  hipMemcpyAsync(bhq, bp2, 512 * 4, hipMemcpyDeviceToDevice, stream);
  // dependent: bofold = bav @ Wo + bo
  vmp_k<<<dim3(32, 1, 1), 512, 0, stream>>>(bav, nullptr, Wo, 0, 0, vpart);
  vmr_k<<<dim3(1, 1, 1), 512, 0, stream>>>(vpart, bo, 32, bofold, 512);
  gemm_mfma_k<64, 64, false, true><<<dim3(8, 16), 256, 0, stream>>>(
      ctxb, WcT, bc, ctxh, 256, 256, 256, 512, 1.f, 0, 0, 0);
  te_k<<<8, 512, 0, stream>>>(Wt, bt, te_table, teSums);
  // teWg[ci] = (te[ci] ⊙ g[1536:]) @ Wf1[1536:,:]
  vmp_k<<<dim3(32, 1, 8), 512, 0, stream>>>(te_table, f_ln_g + 1536, Wf1, 1536, 512, vpart);
  vmr_k<<<dim3(1, 1, 8), 512, 0, stream>>>(vpart, nullptr, 32, teWg, 512);
  // ctx-dependent folds
  gemm_mfma_k<64, 64, false, false><<<dim3(8, 16), 256, 0, stream>>>(
      ctxh, WgT + 1024, nullptr, ctxWg, 512, 512, 2048, 512, 1.f, 0, 0, 0);
  rowsum_k<<<B / 4, 256, 0, stream>>>(ctxh, ctxsums, B);

  // ================= solver [R12 verbatim — proven best] =================
  const float dt = 0.25f;
  auto chain = [&](const float* ycur, const float* kin, float a, int tidx) {
    ln_bf16_k<<<B / 4, 256, 0, stream>>>(ycur, kin, a, pp_ln_g, pp_ln_b,
                                         (__hip_bfloat16*)yln, B);
    gemm_mfma_k<32, 32, true, true><<<dim3(16, 32), 128, 0, stream>>>(
        yln, Wp1T, bp1, hmid, 128, 128, 128, 512, 1.f, 0, 0, 0);
    gemm_mfma_k<32, 64, false, true><<<dim3(16, 32), 128, 0, stream>>>(
        hmid, WhqT, bhq, hqbuf, 512, 512, 512, 1024, 1.f, 0, 0, 0);
    attn_k<<<B, 256, 0, stream>>>((const __hip_bfloat16*)hqbuf, lnsm,
                                  (__hip_bfloat16*)sctx);
    gemm_mfma_k<32, 32, false, true><<<dim3(16, 32), 128, 0, stream>>>(
        sctx, WfoldT, bofold, mobuf, 512, 512, 512, 512, 1.f, 0, 0, 0);
    zstats_k<<<B / 4, 256, 0, stream>>>(hqbuf, mobuf, ctxsums, teSums + 2 * tidx,
                                        murs, B);
    zgemm2_k<<<dim3(16, 32), 128, 0, stream>>>(
        hqbuf, mobuf, ctxWg, teWg + (size_t)tidx * 512, uvec, cbv, murs, WgT, fmid);
  };

  const float* ycur = noise;
  for (int s = 0; s < 4; ++s) {
    // eval 1: k1 = v(y, t0)
    chain(ycur, nullptr, 0.f, 2 * s);
    gemm_mfma_k<32, 32, false, false><<<dim3(4, 32), 128, 0, stream>>>(
        fmid, Wf2T, bf2, k1, 512, 512, 512, 128, 1.f, 0, 0, 0);
    // eval 2: LN(y + dt*k1) fused; ynext = y + dt/2*(k1 + v2)
    chain(ycur, k1, dt, 2 * s + 1);
    float* ynext = (s == 3) ? out : ybuf;
    gemm_heun_k<<<dim3(4, 16), 256, 0, stream>>>(
        fmid, Wf2T, bf2, ycur, k1, 0.5f * dt, ynext);
    ycur = ybuf;
  }
}